// Round 2
// baseline (1055.384 us; speedup 1.0000x reference)
//
#include <hip/hip_runtime.h>
#include <hip/hip_bf16.h>
#include <cstdint>
#include <cstddef>

#define USER_N 40000
#define ITEM_N 40000
#define NN     80000
#define DD     128
#define KK     16
#define EE     1600000

// counting-sort geometry: 313 buckets of 256 rows (313*256 = 80128), 256 edge-groups
#define NB    313
#define NG    256
#define EPG   (EE/NG)     // 6250
#define SCAP  5888        // LDS staging capacity per bucket (mean 5111, sigma ~71)

typedef __attribute__((ext_vector_type(8))) short bf16x8;
typedef __attribute__((ext_vector_type(4))) float f32x4;
typedef unsigned short ushort_t;
typedef unsigned int   uint32;

static __device__ __forceinline__ ushort_t f2bf(float x){
  __hip_bfloat16 h = __float2bfloat16(x);
  return *reinterpret_cast<ushort_t*>(&h);
}
static __device__ __forceinline__ float bflo(uint32 u){ return __uint_as_float(u << 16); }
static __device__ __forceinline__ float bfhi(uint32 u){ return __uint_as_float(u & 0xffff0000u); }
static __device__ __forceinline__ uint32 pack2(float a, float b){
  return (uint32)f2bf(a) | ((uint32)f2bf(b) << 16);
}

// ---------------- init: e_bf = bf16(concat(user,item)); total(d_out) = concat ----------------
__global__ void init_e_total(const float* __restrict__ user_emb, const float* __restrict__ item_emb,
                             ushort_t* __restrict__ e_bf, float* __restrict__ total){
  int idx = blockIdx.x*blockDim.x + threadIdx.x;           // float4 index
  const int n4 = NN*DD/4;
  if (idx >= n4) return;
  const int u4 = USER_N*DD/4;
  float4 v = (idx < u4) ? ((const float4*)user_emb)[idx] : ((const float4*)item_emb)[idx - u4];
  ((float4*)total)[idx] = v;
  ushort4 b; b.x = f2bf(v.x); b.y = f2bf(v.y); b.z = f2bf(v.z); b.w = f2bf(v.w);
  ((ushort4*)e_bf)[idx] = b;
}

// ---------------- weights -> bf16 ----------------
__global__ void cvt_weights(const float* __restrict__ u_in_w, const float* __restrict__ i_in_w,
                            const float* __restrict__ u_out_w, const float* __restrict__ i_out_w,
                            ushort_t* __restrict__ wbf){
  int i = blockIdx.x*256 + threadIdx.x;   // 512 blocks x 256 = 131072
  float v;
  if      (i < 49152)  v = u_in_w[i];
  else if (i < 98304)  v = i_in_w[i - 49152];
  else if (i < 114688) v = u_out_w[i - 98304];
  else                 v = i_out_w[i - 114688];
  wbf[i] = f2bf(v);
}

// ============ CSR build: counting sort by COL bucket, then by ROW (approx-stable) ==========
// The col-first pass makes each row's final edge list ascending in col (to ~±25 cols).
// Concurrent spmm waves then sweep a shared sliding col-window that fits per-XCD L2,
// instead of random-gathering across the whole 20.5MB e_bf table.

// A1: per-group COL-bucket histogram. cntC layout: [b][g] (bucket-major) for the scan.
__global__ __launch_bounds__(256) void sA1_hist(const int* __restrict__ cols,
                                                int* __restrict__ cntC){
  __shared__ int h[NB];
  int g = blockIdx.x, tid = threadIdx.x;
  for (int b = tid; b < NB; b += 256) h[b] = 0;
  __syncthreads();
  int s = g*EPG;
  for (int i = s + tid; i < s + EPG; i += 256)
    atomicAdd(&h[cols[i] >> 8], 1);
  __syncthreads();
  for (int b = tid; b < NB; b += 256) cntC[b*NG + g] = h[b];
}

// S2a: per-256-chunk sums (313 blocks exactly cover 80128 entries)
__global__ void sum313(const int* __restrict__ in, int* __restrict__ bsum){
  __shared__ int s[256];
  s[threadIdx.x] = in[blockIdx.x*256 + threadIdx.x];
  __syncthreads();
  for (int o = 128; o > 0; o >>= 1){
    if (threadIdx.x < o) s[threadIdx.x] += s[threadIdx.x + o];
    __syncthreads();
  }
  if (threadIdx.x == 0) bsum[blockIdx.x] = s[0];
}

// S2b: exclusive scan of the 313 chunk sums
__global__ void scanb(const int* __restrict__ bsum, int* __restrict__ bpre){
  __shared__ int s[512];
  int v = (threadIdx.x < NB) ? bsum[threadIdx.x] : 0;
  s[threadIdx.x] = v;
  __syncthreads();
  for (int o = 1; o < 512; o <<= 1){
    int t = (threadIdx.x >= o) ? s[threadIdx.x - o] : 0;
    __syncthreads();
    s[threadIdx.x] += t;
    __syncthreads();
  }
  if (threadIdx.x < NB) bpre[threadIdx.x] = s[threadIdx.x] - v;
}

// S2c: per-element exclusive prefix
__global__ void scanE(const int* __restrict__ in, const int* __restrict__ bpre,
                      int* __restrict__ baseX){
  __shared__ int s[256];
  int i = blockIdx.x*256 + threadIdx.x;
  int v = in[i];
  s[threadIdx.x] = v;
  __syncthreads();
  for (int o = 1; o < 256; o <<= 1){
    int t = (threadIdx.x >= o) ? s[threadIdx.x - o] : 0;
    __syncthreads();
    s[threadIdx.x] += t;
    __syncthreads();
  }
  baseX[i] = bpre[blockIdx.x] + s[threadIdx.x] - v;
}

// A3: scatter edges into col-bucket-major order. Block-private sequential regions ->
// full write lines. kvC: x=row, y=col, z=val bits (16B for alignment).
__global__ __launch_bounds__(256) void sA3_scatter(const int* __restrict__ rows,
    const int* __restrict__ cols, const float* __restrict__ vals,
    const int* __restrict__ baseC, uint4* __restrict__ kvC){
  __shared__ int cur[NB];
  int g = blockIdx.x, tid = threadIdx.x;
  for (int b = tid; b < NB; b += 256) cur[b] = baseC[b*NG + g];
  __syncthreads();
  int s = g*EPG;
  for (int i = s + tid; i < s + EPG; i += 256){
    int c = cols[i];
    int p = atomicAdd(&cur[c >> 8], 1);
    kvC[p] = make_uint4((uint32)rows[i], (uint32)c, __float_as_uint(vals[i]), 0u);
  }
}

// B1: ROW-bucket histogram over the col-ordered stream
__global__ __launch_bounds__(256) void sB1_hist(const uint4* __restrict__ kvC,
                                                int* __restrict__ cntG){
  __shared__ int h[NB];
  int g = blockIdx.x, tid = threadIdx.x;
  for (int b = tid; b < NB; b += 256) h[b] = 0;
  __syncthreads();
  int s = g*EPG;
  for (int i = s + tid; i < s + EPG; i += 256)
    atomicAdd(&h[kvC[i].x >> 8], 1);
  __syncthreads();
  for (int b = tid; b < NB; b += 256) cntG[b*NG + g] = h[b];
}

// B3: scatter into row-bucket-major kv. Processing position order ~ col order, and the
// per-(bucket,group) regions are position-ordered -> within-row col order survives.
// kv entry: x = (row&255)<<17 | col, y = val bits.
__global__ __launch_bounds__(256) void sB3_scatter(const uint4* __restrict__ kvC,
    const int* __restrict__ baseG, uint2* __restrict__ kv){
  __shared__ int cur[NB];
  int g = blockIdx.x, tid = threadIdx.x;
  for (int b = tid; b < NB; b += 256) cur[b] = baseG[b*NG + g];
  __syncthreads();
  int s = g*EPG;
  for (int i = s + tid; i < s + EPG; i += 256){
    uint4 e = kvC[i];
    int p = atomicAdd(&cur[e.x >> 8], 1);
    kv[p] = make_uint2(((e.x & 255u) << 17) | e.y, e.z);
  }
}

// S4: one block per row-bucket. Stage in LDS, histogram 256 rows, scan, emit row_ptr,
// scatter to final CSR slots. Strided processing keeps ~col order within each row.
__global__ __launch_bounds__(256) void s4_sort(const int* __restrict__ baseG,
    const uint2* __restrict__ kv, int* __restrict__ row_ptr, uint2* __restrict__ csr){
  __shared__ uint2 stage[SCAP];
  __shared__ int hist[256], sc[256], curs[256];
  int b = blockIdx.x, tid = threadIdx.x;
  int start = baseG[b*NG];
  int end   = (b == NB-1) ? EE : baseG[(b+1)*NG];
  int cnt = end - start;
  hist[tid] = 0;
  __syncthreads();
  for (int i = tid; i < cnt; i += 256){
    uint2 e = kv[start + i];
    if (i < SCAP) stage[i] = e;
    atomicAdd(&hist[e.x >> 17], 1);
  }
  __syncthreads();
  int v = hist[tid];
  sc[tid] = v;
  __syncthreads();
  for (int o = 1; o < 256; o <<= 1){
    int t = (tid >= o) ? sc[tid - o] : 0;
    __syncthreads();
    sc[tid] += t;
    __syncthreads();
  }
  int ex = sc[tid] - v;          // exclusive prefix within bucket
  curs[tid] = ex;
  int grow = b*256 + tid;
  if (grow <= NN) row_ptr[grow] = start + ex;   // covers row_ptr[NN] (b=312, tid=128)
  __syncthreads();
  for (int i = tid; i < cnt; i += 256){
    uint2 e = (i < SCAP) ? stage[i] : kv[start + i];
    int r = (int)(e.x >> 17);
    int p = atomicAdd(&curs[r], 1);
    csr[start + p] = make_uint2(e.x & 0x1FFFFu, e.y);
  }
}

// ---------------- SpMM: one wave per row; bf16 gather (256B/row), bf16 output ----------
__global__ __launch_bounds__(256) void spmm_kernel(const int* __restrict__ row_ptr,
    const uint2* __restrict__ csr, const ushort_t* __restrict__ e_bf,
    ushort_t* __restrict__ tmp_bf){
  int wid  = (blockIdx.x*blockDim.x + threadIdx.x) >> 6;
  int lane = threadIdx.x & 63;
  if (wid >= NN) return;
  int s = row_ptr[wid], t = row_ptr[wid+1];
  const uint32* E = (const uint32*)e_bf;   // 2 bf16 per uint
  float ax = 0.f, ay = 0.f;
  int e = s;
  for (; e + 1 < t; e += 2){
    uint2 c0 = csr[e], c1 = csr[e+1];
    float v0 = __uint_as_float(c0.y), v1 = __uint_as_float(c1.y);
    uint32 x0 = E[(size_t)c0.x*64 + lane];
    uint32 x1 = E[(size_t)c1.x*64 + lane];
    ax += v0*bflo(x0) + v1*bflo(x1);
    ay += v0*bfhi(x0) + v1*bfhi(x1);
  }
  if (e < t){
    uint2 c0 = csr[e];
    float v0 = __uint_as_float(c0.y);
    uint32 x0 = E[(size_t)c0.x*64 + lane];
    ax += v0*bflo(x0); ay += v0*bfhi(x0);
  }
  ((uint32*)tmp_bf)[(size_t)wid*64 + lane] = pack2(ax, ay);
}

// ---------------- pos tables (fp32): pos_emb @ W.T + b for Q/K/V, u/i ----------------
__global__ void pos_proj(const float* __restrict__ pos_emb,
                         const float* __restrict__ u_in_w, const float* __restrict__ u_in_b,
                         const float* __restrict__ i_in_w, const float* __restrict__ i_in_b,
                         float* __restrict__ pt){
  int j = blockIdx.x;      // 0..16
  int m = blockIdx.y;      // 0..5
  int d = threadIdx.x;     // 0..127
  if (m >= 4 && j > 0) return;
  const float* w; const float* b; float* out; int roff;
  switch (m){
    case 0: w=u_in_w; b=u_in_b; roff=128; out=pt + j*128;            break; // posK_u
    case 1: w=u_in_w; b=u_in_b; roff=256; out=pt + 17*128 + j*128;   break; // posV_u
    case 2: w=i_in_w; b=i_in_b; roff=128; out=pt + 2*17*128 + j*128; break; // posK_i
    case 3: w=i_in_w; b=i_in_b; roff=256; out=pt + 3*17*128 + j*128; break; // posV_i
    case 4: w=u_in_w; b=u_in_b; roff=0;   out=pt + 4*17*128;         break; // posQ_u
    default:w=i_in_w; b=i_in_b; roff=0;   out=pt + 4*17*128 + 128;   break; // posQ_i
  }
  int row = roff + d;
  float acc = b[row];
  for (int c = 0; c < DD; c++) acc += pos_emb[j*DD + c] * w[row*DD + c];
  out[d] = acc;
}

// ---- wave-private LDS transpose of a 16x128 MFMA C-tile, then coalesced bf16 stores ----
static __device__ __forceinline__ void tile_store_bf16(float* __restrict__ T,
    const f32x4* acc, ushort_t* __restrict__ dst, int row0, int jg, int lr, int l){
  #pragma unroll
  for (int r=0;r<4;r++){
    int row = jg*4 + r;
    #pragma unroll
    for (int ct=0;ct<8;ct++) T[row*132 + ct*16 + lr] = acc[ct][r];
  }
  // wave-private: no barrier needed, compiler orders ds via lgkmcnt
  #pragma unroll
  for (int i=0;i<4;i++){
    int row = l & 15;
    int p = (l >> 4) + 4*i;          // 16B-pair index 0..15 (8 cols each)
    const float* src = &T[row*132 + p*8];
    float4 a = *(const float4*)src;
    float4 b = *(const float4*)(src + 4);
    uint4 w = make_uint4(pack2(a.x,a.y), pack2(a.z,a.w), pack2(b.x,b.y), pack2(b.z,b.w));
    *(uint4*)&dst[(size_t)(row0 + row)*128 + p*8] = w;
  }
}

// ------------- fused 5-matrix GEMM: grid (5, NN/64); x-fastest dispatch => 5 consecutive
// blocks share the same 64 A-rows -> A fetched ~once from L2 instead of 5x. -------------
__global__ __launch_bounds__(256,4) void gemm16x5(const ushort_t* __restrict__ A,
    const ushort_t* __restrict__ wbf, ushort_t* __restrict__ Qb,
    ushort_t* __restrict__ Ku, ushort_t* __restrict__ Vu,
    ushort_t* __restrict__ Ki, ushort_t* __restrict__ Vi){
  __shared__ float lds[4][16*132];
  int tid = threadIdx.x;
  int wvi = tid >> 6, l = tid & 63, lr = l & 15, jg = l >> 4;
  int row0 = blockIdx.y*64 + wvi*16;
  const ushort_t* W0; const ushort_t* W1; ushort_t* dst;
  switch (blockIdx.x){
    case 0:  W0 = wbf;           W1 = wbf + 3*16384; dst = Qb; break;  // Q: wq_u / wq_i
    case 1:  W0 = wbf + 16384;   W1 = W0;            dst = Ku; break;  // wk_u
    case 2:  W0 = wbf + 2*16384; W1 = W0;            dst = Vu; break;  // wv_u
    case 3:  W0 = wbf + 4*16384; W1 = W0;            dst = Ki; break;  // wk_i
    default: W0 = wbf + 5*16384; W1 = W0;            dst = Vi; break;  // wv_i
  }
  const bf16x8* Av = (const bf16x8*)A;
  const bf16x8* Bw = (const bf16x8*)((row0 < USER_N) ? W0 : W1);
  f32x4 acc[8];
  #pragma unroll
  for (int c=0;c<8;c++) acc[c]=(f32x4){0,0,0,0};
  #pragma unroll
  for (int kc = 0; kc < 4; kc++){
    int ko = kc*4 + jg;
    bf16x8 a = Av[(size_t)(row0 + lr)*16 + ko];
    #pragma unroll
    for (int ct=0;ct<8;ct++)
      acc[ct] = __builtin_amdgcn_mfma_f32_16x16x32_bf16(a, Bw[(size_t)(ct*16+lr)*16 + ko], acc[ct], 0, 0, 0);
  }
  tile_store_bf16(lds[wvi], acc, dst, row0, jg, lr, l);
}

// ---------------- out-projection (wave-uniform weight select) + coalesced epilogue -------
__global__ __launch_bounds__(256,4) void out_all(const ushort_t* __restrict__ A,
    const ushort_t* __restrict__ wo_u, const ushort_t* __restrict__ wo_i,
    const float* __restrict__ bu, const float* __restrict__ bi_,
    const ushort_t* __restrict__ resid_bf, ushort_t* __restrict__ e_bf,
    float* __restrict__ total, float* __restrict__ total2){
  __shared__ float lds[4][16*132];
  int tid = threadIdx.x;
  int wvi = tid >> 6, l = tid & 63, lr = l & 15, jg = l >> 4;
  int row0 = blockIdx.x*64 + wvi*16;
  bool isU = row0 < USER_N;
  const bf16x8* Av = (const bf16x8*)A;
  const bf16x8* Bw = (const bf16x8*)(isU ? wo_u : wo_i);
  const float*  bias = isU ? bu : bi_;
  f32x4 acc[8];
  #pragma unroll
  for (int c=0;c<8;c++) acc[c]=(f32x4){0,0,0,0};
  #pragma unroll
  for (int kc = 0; kc < 4; kc++){
    int ko = kc*4 + jg;
    bf16x8 a = Av[(size_t)(row0 + lr)*16 + ko];
    #pragma unroll
    for (int ct=0;ct<8;ct++)
      acc[ct] = __builtin_amdgcn_mfma_f32_16x16x32_bf16(a, Bw[(size_t)(ct*16+lr)*16 + ko], acc[ct], 0, 0, 0);
  }
  float* T = lds[wvi];
  #pragma unroll
  for (int r=0;r<4;r++){
    int row = jg*4 + r;
    #pragma unroll
    for (int ct=0;ct<8;ct++) T[row*132 + ct*16 + lr] = acc[ct][r];
  }
  #pragma unroll
  for (int i=0;i<4;i++){
    int row = l & 15;
    int p = (l >> 4) + 4*i;
    int grow = row0 + row;
    size_t o = (size_t)grow*128 + p*8;
    const float* src = &T[row*132 + p*8];
    float4 a = *(const float4*)src;
    float4 b = *(const float4*)(src + 4);
    float4 ba = *(const float4*)&bias[p*8];
    float4 bb = *(const float4*)&bias[p*8 + 4];
    uint4 rr = *(const uint4*)&resid_bf[o];
    a.x += ba.x + bflo(rr.x); a.y += ba.y + bfhi(rr.x);
    a.z += ba.z + bflo(rr.y); a.w += ba.w + bfhi(rr.y);
    b.x += bb.x + bflo(rr.z); b.y += bb.y + bfhi(rr.z);
    b.z += bb.z + bflo(rr.w); b.w += bb.w + bfhi(rr.w);
    *(uint4*)&e_bf[o] = make_uint4(pack2(a.x,a.y), pack2(a.z,a.w), pack2(b.x,b.y), pack2(b.z,b.w));
    float4 t0 = *(const float4*)&total[o];
    float4 t1 = *(const float4*)&total[o + 4];
    t0.x += a.x; t0.y += a.y; t0.z += a.z; t0.w += a.w;
    t1.x += b.x; t1.y += b.y; t1.z += b.z; t1.w += b.w;
    *(float4*)&total[o]     = t0;
    *(float4*)&total[o + 4] = t1;
    if (total2){
      *(float4*)&total2[o]     = t0;
      *(float4*)&total2[o + 4] = t1;
    }
  }
}

// ---------------- attention: one wave per node, L=17, H=4, dh=32; bf16 Q/K/V --------------
// K/V gathers iterate the 16 samples in ASCENDING order (softmax is order-invariant;
// pos tables indexed by the recovered original j). Concurrent waves sweep a shared
// sliding col-window -> per-XCD L2 captures the K/V gather instead of random misses.
__global__ __launch_bounds__(256) void attn_kernel(const ushort_t* __restrict__ QP,
    const ushort_t* __restrict__ KP, const ushort_t* __restrict__ VP,
    const int* __restrict__ samples,
    const float* __restrict__ posQ, const float* __restrict__ posK, const float* __restrict__ posV,
    ushort_t* __restrict__ O, int base, int cnt){
  int wid  = (blockIdx.x*blockDim.x + threadIdx.x) >> 6;
  int lane = threadIdx.x & 63;
  if (wid >= cnt) return;                       // wave-uniform exit
  int n = base + wid;
  const uint32* Q2 = (const uint32*)QP;
  const uint32* K2 = (const uint32*)KP;
  const uint32* V2 = (const uint32*)VP;
  const float2* pQ2 = (const float2*)posQ;
  const float2* pK2 = (const float2*)posK;
  const float2* pV2 = (const float2*)posV;
  float2 pq = pQ2[lane];
  uint32 qu = Q2[(size_t)n*64 + lane];
  float qx = bflo(qu) + pq.x, qy = bfhi(qu) + pq.y;
  int smp = (lane < KK) ? samples[(size_t)n*KK + lane] : 0;
  // rank of each lane's sample (strict total order via lane tie-break)
  int rank = 0;
  #pragma unroll
  for (int t = 0; t < KK; t++){
    int v = __shfl(smp, t, 64);
    rank += (v < smp) || (v == smp && t < lane);
  }
  float sc[17], vx[17], vy[17];
  #pragma unroll
  for (int t = 0; t < 17; t++){
    int row, j;
    if (t == 0){ row = n; j = 0; }
    else {
      unsigned long long mask = __ballot(lane < KK && rank == t-1);
      int src = __builtin_ctzll(mask);
      row = __shfl(smp, src, 64);
      j = src + 1;
    }
    uint32 ku = K2[(size_t)row*64 + lane];
    uint32 vu = V2[(size_t)row*64 + lane];
    float2 pk = pK2[j*64 + lane];
    float2 pv = pV2[j*64 + lane];
    float kx = bflo(ku) + pk.x, ky = bfhi(ku) + pk.y;
    vx[t] = bflo(vu) + pv.x; vy[t] = bfhi(vu) + pv.y;
    float p = qx*kx + qy*ky;              // head = lane>>4 (dims 2*lane, 2*lane+1)
    p += __shfl_xor(p, 1, 64);
    p += __shfl_xor(p, 2, 64);
    p += __shfl_xor(p, 4, 64);
    p += __shfl_xor(p, 8, 64);
    sc[t] = p * 0.17677669529663687f;     // 1/sqrt(32)
  }
  float m = sc[0];
  #pragma unroll
  for (int t=1;t<17;t++) m = fmaxf(m, sc[t]);
  float ssum = 0.f;
  #pragma unroll
  for (int t=0;t<17;t++){ sc[t] = __expf(sc[t]-m); ssum += sc[t]; }
  float inv = 1.f/ssum;
  float ox=0.f, oy=0.f;
  #pragma unroll
  for (int t=0;t<17;t++){ ox += sc[t]*vx[t]; oy += sc[t]*vy[t]; }
  ((uint32*)O)[(size_t)n*64 + lane] = pack2(ox*inv, oy*inv);
}

extern "C" void kernel_launch(void* const* d_in, const int* in_sizes, int n_in,
                              void* d_out, int out_size, void* d_ws, size_t ws_size,
                              hipStream_t stream){
  const int*   adj_rows = (const int*)d_in[0];
  const int*   adj_cols = (const int*)d_in[1];
  const float* adj_vals = (const float*)d_in[2];
  const int*   samples  = (const int*)d_in[3];
  const float* user_emb = (const float*)d_in[4];
  const float* item_emb = (const float*)d_in[5];
  const float* pos_emb  = (const float*)d_in[6];
  const float* u_in_w   = (const float*)d_in[7];
  const float* u_in_b   = (const float*)d_in[8];
  const float* u_out_w  = (const float*)d_in[9];
  const float* u_out_b  = (const float*)d_in[10];
  const float* i_in_w   = (const float*)d_in[11];
  const float* i_in_b   = (const float*)d_in[12];
  const float* i_out_w  = (const float*)d_in[13];
  const float* i_out_b  = (const float*)d_in[14];
  float* out = (float*)d_out;

  char* ws = (char*)d_ws;
  size_t off = 0;
  auto alloc = [&](size_t bytes)->char*{
    char* p = ws + off; off += (bytes + 255) & ~(size_t)255; return p;
  };
  ushort_t* tmp_bf  = (ushort_t*)alloc((size_t)NN*DD*2);
  ushort_t* e_bf    = (ushort_t*)alloc((size_t)NN*DD*2);
  ushort_t* Qb      = (ushort_t*)alloc((size_t)NN*DD*2);
  ushort_t* Ku      = (ushort_t*)alloc((size_t)NN*DD*2);
  ushort_t* Vu      = (ushort_t*)alloc((size_t)NN*DD*2);
  ushort_t* Ki      = (ushort_t*)alloc((size_t)NN*DD*2);
  ushort_t* Vi      = (ushort_t*)alloc((size_t)NN*DD*2);
  ushort_t* Ob      = (ushort_t*)alloc((size_t)NN*DD*2);
  uint2*    csr     = (uint2*)   alloc((size_t)EE*8);
  int*      cntG    = (int*)     alloc((size_t)(NB*NG)*4);
  int*      baseG   = (int*)     alloc((size_t)(NB*NG)*4);
  int*      row_ptr = (int*)     alloc((size_t)(NN+1)*4);
  int*      bsum    = (int*)     alloc(320*4);
  int*      bpre    = (int*)     alloc(320*4);
  float*    pt      = (float*)   alloc((size_t)8960*4);
  ushort_t* wbf     = (ushort_t*)alloc((size_t)131072*2);

  // Aliases (all stream-ordered, safe under graph replay):
  //  kv  (12.8MB) -> Ob  : Ob first written by attn, long after s4 consumed kv.
  //  kvC (25.6MB) -> Qb+Ku : both first written by gemm16x5, after sB3 consumed kvC.
  //  cntC/baseC (320KB ea) -> csr : csr first written by s4, after sA3 consumed baseC.
  uint2* kv  = (uint2*)Ob;
  uint4* kvC = (uint4*)Qb;
  int*   cntC  = (int*)csr;
  int*   baseC = (int*)csr + NB*NG;

  float* posK_u = pt;
  float* posV_u = pt + 17*128;
  float* posK_i = pt + 2*17*128;
  float* posV_i = pt + 3*17*128;
  float* posQ_u = pt + 4*17*128;
  float* posQ_i = pt + 4*17*128 + 128;

  ushort_t* wo_u = wbf + 6*16384;
  ushort_t* wo_i = wbf + 7*16384;

  init_e_total<<<NN*DD/4/256, 256, 0, stream>>>(user_emb, item_emb, e_bf, out);
  // ---- CSR build: col-bucket sort, then row sort (approx-stable => col order in rows) ----
  sA1_hist<<<NG, 256, 0, stream>>>(adj_cols, cntC);
  sum313<<<NB, 256, 0, stream>>>(cntC, bsum);
  scanb<<<1, 512, 0, stream>>>(bsum, bpre);
  scanE<<<NB, 256, 0, stream>>>(cntC, bpre, baseC);
  sA3_scatter<<<NG, 256, 0, stream>>>(adj_rows, adj_cols, adj_vals, baseC, kvC);
  sB1_hist<<<NG, 256, 0, stream>>>(kvC, cntG);
  sum313<<<NB, 256, 0, stream>>>(cntG, bsum);
  scanb<<<1, 512, 0, stream>>>(bsum, bpre);
  scanE<<<NB, 256, 0, stream>>>(cntG, bpre, baseG);
  sB3_scatter<<<NG, 256, 0, stream>>>(kvC, baseG, kv);
  s4_sort<<<NB, 256, 0, stream>>>(baseG, kv, row_ptr, csr);
  pos_proj<<<dim3(17,6), 128, 0, stream>>>(pos_emb, u_in_w, u_in_b, i_in_w, i_in_b, pt);
  cvt_weights<<<512, 256, 0, stream>>>(u_in_w, i_in_w, u_out_w, i_out_w, wbf);

  for (int it = 0; it < 2; it++){
    float* tot2 = (it == 1) ? (out + (size_t)NN*DD) : nullptr;
    spmm_kernel<<<NN/4, 256, 0, stream>>>(row_ptr, csr, e_bf, tmp_bf);
    gemm16x5<<<dim3(5, NN/64), 256, 0, stream>>>(tmp_bf, wbf, Qb, Ku, Vu, Ki, Vi);
    attn_kernel<<<USER_N/4, 256, 0, stream>>>(Qb, Ku, Vu, samples, posQ_u, posK_u, posV_u,
                                              Ob, 0, USER_N);
    attn_kernel<<<ITEM_N/4, 256, 0, stream>>>(Qb, Ki, Vi, samples, posQ_i, posK_i, posV_i,
                                              Ob, USER_N, ITEM_N);
    out_all<<<NN/64, 256, 0, stream>>>(Ob, wo_u, wo_i, u_out_b, i_out_b,
                                       tmp_bf, e_bf, out, tot2);
  }
}

// Round 3
// 925.076 us; speedup vs baseline: 1.1409x; 1.1409x over previous
//
#include <hip/hip_runtime.h>
#include <hip/hip_bf16.h>
#include <cstdint>
#include <cstddef>

#define USER_N 40000
#define ITEM_N 40000
#define NN     80000
#define DD     128
#define KK     16
#define EE     1600000

// counting-sort geometry: 313 buckets of 256 rows (313*256 = 80128), 256 edge-groups
#define NB    313
#define NG    256
#define EPG   (EE/NG)     // 6250
#define SCAP  5888        // LDS staging capacity per bucket (mean 5111, sigma ~71)

typedef __attribute__((ext_vector_type(8))) short bf16x8;
typedef __attribute__((ext_vector_type(4))) float f32x4;
typedef unsigned short ushort_t;
typedef unsigned int   uint32;

static __device__ __forceinline__ ushort_t f2bf(float x){
  __hip_bfloat16 h = __float2bfloat16(x);
  return *reinterpret_cast<ushort_t*>(&h);
}
static __device__ __forceinline__ float bflo(uint32 u){ return __uint_as_float(u << 16); }
static __device__ __forceinline__ float bfhi(uint32 u){ return __uint_as_float(u & 0xffff0000u); }
static __device__ __forceinline__ uint32 pack2(float a, float b){
  return (uint32)f2bf(a) | ((uint32)f2bf(b) << 16);
}

// ---------------- init: e_bf = bf16(concat(user,item)); total(d_out) = concat ----------------
__global__ void init_e_total(const float* __restrict__ user_emb, const float* __restrict__ item_emb,
                             ushort_t* __restrict__ e_bf, float* __restrict__ total){
  int idx = blockIdx.x*blockDim.x + threadIdx.x;           // float4 index
  const int n4 = NN*DD/4;
  if (idx >= n4) return;
  const int u4 = USER_N*DD/4;
  float4 v = (idx < u4) ? ((const float4*)user_emb)[idx] : ((const float4*)item_emb)[idx - u4];
  ((float4*)total)[idx] = v;
  ushort4 b; b.x = f2bf(v.x); b.y = f2bf(v.y); b.z = f2bf(v.z); b.w = f2bf(v.w);
  ((ushort4*)e_bf)[idx] = b;
}

// ---------------- weights -> bf16 ----------------
__global__ void cvt_weights(const float* __restrict__ u_in_w, const float* __restrict__ i_in_w,
                            const float* __restrict__ u_out_w, const float* __restrict__ i_out_w,
                            ushort_t* __restrict__ wbf){
  int i = blockIdx.x*256 + threadIdx.x;   // 512 blocks x 256 = 131072
  float v;
  if      (i < 49152)  v = u_in_w[i];
  else if (i < 98304)  v = i_in_w[i - 49152];
  else if (i < 114688) v = u_out_w[i - 98304];
  else                 v = i_out_w[i - 114688];
  wbf[i] = f2bf(v);
}

// ============ CSR build: counting sort by COL bucket, then by ROW (approx-stable) ==========
// The col-first pass makes each row's final edge list ascending in col (to ~±25 cols).
// Concurrent spmm waves then sweep a shared sliding col-window that fits per-XCD L2,
// instead of random-gathering across the whole 20.5MB e_bf table.

// A1: per-group COL-bucket histogram. cntC layout: [b][g] (bucket-major) for the scan.
__global__ __launch_bounds__(256) void sA1_hist(const int* __restrict__ cols,
                                                int* __restrict__ cntC){
  __shared__ int h[NB];
  int g = blockIdx.x, tid = threadIdx.x;
  for (int b = tid; b < NB; b += 256) h[b] = 0;
  __syncthreads();
  int s = g*EPG;
  for (int i = s + tid; i < s + EPG; i += 256)
    atomicAdd(&h[cols[i] >> 8], 1);
  __syncthreads();
  for (int b = tid; b < NB; b += 256) cntC[b*NG + g] = h[b];
}

// S2a: per-256-chunk sums (313 blocks exactly cover 80128 entries)
__global__ void sum313(const int* __restrict__ in, int* __restrict__ bsum){
  __shared__ int s[256];
  s[threadIdx.x] = in[blockIdx.x*256 + threadIdx.x];
  __syncthreads();
  for (int o = 128; o > 0; o >>= 1){
    if (threadIdx.x < o) s[threadIdx.x] += s[threadIdx.x + o];
    __syncthreads();
  }
  if (threadIdx.x == 0) bsum[blockIdx.x] = s[0];
}

// S2b: exclusive scan of the 313 chunk sums
__global__ void scanb(const int* __restrict__ bsum, int* __restrict__ bpre){
  __shared__ int s[512];
  int v = (threadIdx.x < NB) ? bsum[threadIdx.x] : 0;
  s[threadIdx.x] = v;
  __syncthreads();
  for (int o = 1; o < 512; o <<= 1){
    int t = (threadIdx.x >= o) ? s[threadIdx.x - o] : 0;
    __syncthreads();
    s[threadIdx.x] += t;
    __syncthreads();
  }
  if (threadIdx.x < NB) bpre[threadIdx.x] = s[threadIdx.x] - v;
}

// S2c: per-element exclusive prefix
__global__ void scanE(const int* __restrict__ in, const int* __restrict__ bpre,
                      int* __restrict__ baseX){
  __shared__ int s[256];
  int i = blockIdx.x*256 + threadIdx.x;
  int v = in[i];
  s[threadIdx.x] = v;
  __syncthreads();
  for (int o = 1; o < 256; o <<= 1){
    int t = (threadIdx.x >= o) ? s[threadIdx.x - o] : 0;
    __syncthreads();
    s[threadIdx.x] += t;
    __syncthreads();
  }
  baseX[i] = bpre[blockIdx.x] + s[threadIdx.x] - v;
}

// A3: scatter edges into col-bucket-major order. Block-private sequential regions ->
// full write lines. kvC: x=row, y=col, z=val bits (16B for alignment).
__global__ __launch_bounds__(256) void sA3_scatter(const int* __restrict__ rows,
    const int* __restrict__ cols, const float* __restrict__ vals,
    const int* __restrict__ baseC, uint4* __restrict__ kvC){
  __shared__ int cur[NB];
  int g = blockIdx.x, tid = threadIdx.x;
  for (int b = tid; b < NB; b += 256) cur[b] = baseC[b*NG + g];
  __syncthreads();
  int s = g*EPG;
  for (int i = s + tid; i < s + EPG; i += 256){
    int c = cols[i];
    int p = atomicAdd(&cur[c >> 8], 1);
    kvC[p] = make_uint4((uint32)rows[i], (uint32)c, __float_as_uint(vals[i]), 0u);
  }
}

// B1: ROW-bucket histogram over the col-ordered stream
__global__ __launch_bounds__(256) void sB1_hist(const uint4* __restrict__ kvC,
                                                int* __restrict__ cntG){
  __shared__ int h[NB];
  int g = blockIdx.x, tid = threadIdx.x;
  for (int b = tid; b < NB; b += 256) h[b] = 0;
  __syncthreads();
  int s = g*EPG;
  for (int i = s + tid; i < s + EPG; i += 256)
    atomicAdd(&h[kvC[i].x >> 8], 1);
  __syncthreads();
  for (int b = tid; b < NB; b += 256) cntG[b*NG + g] = h[b];
}

// B3: scatter into row-bucket-major kv. Processing position order ~ col order, and the
// per-(bucket,group) regions are position-ordered -> within-row col order survives.
// kv entry: x = (row&255)<<17 | col, y = val bits.
__global__ __launch_bounds__(256) void sB3_scatter(const uint4* __restrict__ kvC,
    const int* __restrict__ baseG, uint2* __restrict__ kv){
  __shared__ int cur[NB];
  int g = blockIdx.x, tid = threadIdx.x;
  for (int b = tid; b < NB; b += 256) cur[b] = baseG[b*NG + g];
  __syncthreads();
  int s = g*EPG;
  for (int i = s + tid; i < s + EPG; i += 256){
    uint4 e = kvC[i];
    int p = atomicAdd(&cur[e.x >> 8], 1);
    kv[p] = make_uint2(((e.x & 255u) << 17) | e.y, e.z);
  }
}

// S4: one block per row-bucket. Stage in LDS, histogram 256 rows, scan, emit row_ptr,
// scatter to final CSR slots. Strided processing keeps ~col order within each row.
__global__ __launch_bounds__(256) void s4_sort(const int* __restrict__ baseG,
    const uint2* __restrict__ kv, int* __restrict__ row_ptr, uint2* __restrict__ csr){
  __shared__ uint2 stage[SCAP];
  __shared__ int hist[256], sc[256], curs[256];
  int b = blockIdx.x, tid = threadIdx.x;
  int start = baseG[b*NG];
  int end   = (b == NB-1) ? EE : baseG[(b+1)*NG];
  int cnt = end - start;
  hist[tid] = 0;
  __syncthreads();
  for (int i = tid; i < cnt; i += 256){
    uint2 e = kv[start + i];
    if (i < SCAP) stage[i] = e;
    atomicAdd(&hist[e.x >> 17], 1);
  }
  __syncthreads();
  int v = hist[tid];
  sc[tid] = v;
  __syncthreads();
  for (int o = 1; o < 256; o <<= 1){
    int t = (tid >= o) ? sc[tid - o] : 0;
    __syncthreads();
    sc[tid] += t;
    __syncthreads();
  }
  int ex = sc[tid] - v;          // exclusive prefix within bucket
  curs[tid] = ex;
  int grow = b*256 + tid;
  if (grow <= NN) row_ptr[grow] = start + ex;   // covers row_ptr[NN] (b=312, tid=128)
  __syncthreads();
  for (int i = tid; i < cnt; i += 256){
    uint2 e = (i < SCAP) ? stage[i] : kv[start + i];
    int r = (int)(e.x >> 17);
    int p = atomicAdd(&curs[r], 1);
    csr[start + p] = make_uint2(e.x & 0x1FFFFu, e.y);
  }
}

// ---------------- SpMM: one wave per row; bf16 gather (256B/row), bf16 output ----------
__global__ __launch_bounds__(256) void spmm_kernel(const int* __restrict__ row_ptr,
    const uint2* __restrict__ csr, const ushort_t* __restrict__ e_bf,
    ushort_t* __restrict__ tmp_bf){
  int wid  = (blockIdx.x*blockDim.x + threadIdx.x) >> 6;
  int lane = threadIdx.x & 63;
  if (wid >= NN) return;
  int s = row_ptr[wid], t = row_ptr[wid+1];
  const uint32* E = (const uint32*)e_bf;   // 2 bf16 per uint
  float ax = 0.f, ay = 0.f;
  int e = s;
  for (; e + 1 < t; e += 2){
    uint2 c0 = csr[e], c1 = csr[e+1];
    float v0 = __uint_as_float(c0.y), v1 = __uint_as_float(c1.y);
    uint32 x0 = E[(size_t)c0.x*64 + lane];
    uint32 x1 = E[(size_t)c1.x*64 + lane];
    ax += v0*bflo(x0) + v1*bflo(x1);
    ay += v0*bfhi(x0) + v1*bfhi(x1);
  }
  if (e < t){
    uint2 c0 = csr[e];
    float v0 = __uint_as_float(c0.y);
    uint32 x0 = E[(size_t)c0.x*64 + lane];
    ax += v0*bflo(x0); ay += v0*bfhi(x0);
  }
  ((uint32*)tmp_bf)[(size_t)wid*64 + lane] = pack2(ax, ay);
}

// ---------------- pos tables (fp32): pos_emb @ W.T + b for Q/K/V, u/i ----------------
__global__ void pos_proj(const float* __restrict__ pos_emb,
                         const float* __restrict__ u_in_w, const float* __restrict__ u_in_b,
                         const float* __restrict__ i_in_w, const float* __restrict__ i_in_b,
                         float* __restrict__ pt){
  int j = blockIdx.x;      // 0..16
  int m = blockIdx.y;      // 0..5
  int d = threadIdx.x;     // 0..127
  if (m >= 4 && j > 0) return;
  const float* w; const float* b; float* out; int roff;
  switch (m){
    case 0: w=u_in_w; b=u_in_b; roff=128; out=pt + j*128;            break; // posK_u
    case 1: w=u_in_w; b=u_in_b; roff=256; out=pt + 17*128 + j*128;   break; // posV_u
    case 2: w=i_in_w; b=i_in_b; roff=128; out=pt + 2*17*128 + j*128; break; // posK_i
    case 3: w=i_in_w; b=i_in_b; roff=256; out=pt + 3*17*128 + j*128; break; // posV_i
    case 4: w=u_in_w; b=u_in_b; roff=0;   out=pt + 4*17*128;         break; // posQ_u
    default:w=i_in_w; b=i_in_b; roff=0;   out=pt + 4*17*128 + 128;   break; // posQ_i
  }
  int row = roff + d;
  float acc = b[row];
  for (int c = 0; c < DD; c++) acc += pos_emb[j*DD + c] * w[row*DD + c];
  out[d] = acc;
}

// ---- wave-private LDS transpose of a 16x128 MFMA C-tile, then coalesced bf16 stores ----
static __device__ __forceinline__ void tile_store_bf16(float* __restrict__ T,
    const f32x4* acc, ushort_t* __restrict__ dst, int row0, int jg, int lr, int l){
  #pragma unroll
  for (int r=0;r<4;r++){
    int row = jg*4 + r;
    #pragma unroll
    for (int ct=0;ct<8;ct++) T[row*132 + ct*16 + lr] = acc[ct][r];
  }
  // wave-private: no barrier needed, compiler orders ds via lgkmcnt
  #pragma unroll
  for (int i=0;i<4;i++){
    int row = l & 15;
    int p = (l >> 4) + 4*i;          // 16B-pair index 0..15 (8 cols each)
    const float* src = &T[row*132 + p*8];
    float4 a = *(const float4*)src;
    float4 b = *(const float4*)(src + 4);
    uint4 w = make_uint4(pack2(a.x,a.y), pack2(a.z,a.w), pack2(b.x,b.y), pack2(b.z,b.w));
    *(uint4*)&dst[(size_t)(row0 + row)*128 + p*8] = w;
  }
}

// ------- 5-in-1 GEMM: 1250 blocks; A-frags register-resident, reused across 5 weight
// matrices; weights staged global->LDS in 16KB halves (XOR-swizzled) so B-reads never
// touch L1/L2 per-wave. Per-block weight traffic: 160KB from L2 (vs 640KB per-wave). ---
__global__ __launch_bounds__(256,3) void gemm5(const ushort_t* __restrict__ A,
    const ushort_t* __restrict__ wbf, ushort_t* __restrict__ Qb,
    ushort_t* __restrict__ Ku, ushort_t* __restrict__ Vu,
    ushort_t* __restrict__ Ki, ushort_t* __restrict__ Vi){
  __shared__ ushort_t wlds[8192];          // 16KB: one half-matrix (64 rows x 128 k)
  __shared__ float   tlds[4][16*132];      // 33.8KB transpose buffers (wave-private)
  int tid = threadIdx.x;
  int wvi = tid >> 6, l = tid & 63, lr = l & 15, jg = l >> 4;
  int row0 = blockIdx.x*64 + wvi*16;
  bool isU = (blockIdx.x*64) < USER_N;     // block-uniform (64 | 40000)

  // A fragments: 16 rows x 128 k in registers, reused for all 5 matrices
  const bf16x8* Av = (const bf16x8*)A;
  bf16x8 aFrag[4];
  #pragma unroll
  for (int kc = 0; kc < 4; kc++)
    aFrag[kc] = Av[(size_t)(row0 + lr)*16 + kc*4 + jg];

  const ushort_t* Wm[5];
  ushort_t* Dm[5];
  Wm[0] = isU ? wbf : (wbf + 3*16384);  Dm[0] = Qb;   // wq_u / wq_i
  Wm[1] = wbf + 16384;                  Dm[1] = Ku;   // wk_u
  Wm[2] = wbf + 2*16384;                Dm[2] = Vu;   // wv_u
  Wm[3] = wbf + 4*16384;                Dm[3] = Ki;   // wk_i
  Wm[4] = wbf + 5*16384;                Dm[4] = Vi;   // wv_i

  #pragma unroll
  for (int m = 0; m < 5; m++){
    f32x4 acc[8];
    #pragma unroll
    for (int c=0;c<8;c++) acc[c]=(f32x4){0,0,0,0};
    #pragma unroll
    for (int h = 0; h < 2; h++){
      __syncthreads();                               // prev readers done
      // stage half h: rows 64h..64h+63 of W (16KB), swizzled byte ^= (row&7)<<4
      const uint4* src = (const uint4*)(Wm[m] + h*8192);
      #pragma unroll
      for (int r = 0; r < 4; r++){
        int u = r*256 + tid;                         // 16B unit 0..1023
        uint32 sw = ((uint32)u*16) ^ (((uint32)(u>>4)&7u)<<4);
        *(uint4*)((char*)wlds + sw) = src[u];
      }
      __syncthreads();                               // staging visible
      #pragma unroll
      for (int kc = 0; kc < 4; kc++){
        #pragma unroll
        for (int ct = 0; ct < 4; ct++){
          uint32 rowh = (uint32)(ct*16 + lr);
          uint32 byte = (rowh*256u + (uint32)(kc*4 + jg)*16u) ^ ((rowh&7u)<<4);
          bf16x8 b = *(const bf16x8*)((const char*)wlds + byte);
          acc[h*4+ct] = __builtin_amdgcn_mfma_f32_16x16x32_bf16(aFrag[kc], b, acc[h*4+ct], 0, 0, 0);
        }
      }
    }
    tile_store_bf16(tlds[wvi], acc, Dm[m], row0, jg, lr, l);
  }
}

// ---------------- out-projection (wave-uniform weight select) + coalesced epilogue -------
__global__ __launch_bounds__(256,4) void out_all(const ushort_t* __restrict__ A,
    const ushort_t* __restrict__ wo_u, const ushort_t* __restrict__ wo_i,
    const float* __restrict__ bu, const float* __restrict__ bi_,
    const ushort_t* __restrict__ resid_bf, ushort_t* __restrict__ e_bf,
    float* __restrict__ total, float* __restrict__ total2){
  __shared__ float lds[4][16*132];
  int tid = threadIdx.x;
  int wvi = tid >> 6, l = tid & 63, lr = l & 15, jg = l >> 4;
  int row0 = blockIdx.x*64 + wvi*16;
  bool isU = row0 < USER_N;
  const bf16x8* Av = (const bf16x8*)A;
  const bf16x8* Bw = (const bf16x8*)(isU ? wo_u : wo_i);
  const float*  bias = isU ? bu : bi_;
  f32x4 acc[8];
  #pragma unroll
  for (int c=0;c<8;c++) acc[c]=(f32x4){0,0,0,0};
  #pragma unroll
  for (int kc = 0; kc < 4; kc++){
    int ko = kc*4 + jg;
    bf16x8 a = Av[(size_t)(row0 + lr)*16 + ko];
    #pragma unroll
    for (int ct=0;ct<8;ct++)
      acc[ct] = __builtin_amdgcn_mfma_f32_16x16x32_bf16(a, Bw[(size_t)(ct*16+lr)*16 + ko], acc[ct], 0, 0, 0);
  }
  float* T = lds[wvi];
  #pragma unroll
  for (int r=0;r<4;r++){
    int row = jg*4 + r;
    #pragma unroll
    for (int ct=0;ct<8;ct++) T[row*132 + ct*16 + lr] = acc[ct][r];
  }
  #pragma unroll
  for (int i=0;i<4;i++){
    int row = l & 15;
    int p = (l >> 4) + 4*i;
    int grow = row0 + row;
    size_t o = (size_t)grow*128 + p*8;
    const float* src = &T[row*132 + p*8];
    float4 a = *(const float4*)src;
    float4 b = *(const float4*)(src + 4);
    float4 ba = *(const float4*)&bias[p*8];
    float4 bb = *(const float4*)&bias[p*8 + 4];
    uint4 rr = *(const uint4*)&resid_bf[o];
    a.x += ba.x + bflo(rr.x); a.y += ba.y + bfhi(rr.x);
    a.z += ba.z + bflo(rr.y); a.w += ba.w + bfhi(rr.y);
    b.x += bb.x + bflo(rr.z); b.y += bb.y + bfhi(rr.z);
    b.z += bb.z + bflo(rr.w); b.w += bb.w + bfhi(rr.w);
    *(uint4*)&e_bf[o] = make_uint4(pack2(a.x,a.y), pack2(a.z,a.w), pack2(b.x,b.y), pack2(b.z,b.w));
    float4 t0 = *(const float4*)&total[o];
    float4 t1 = *(const float4*)&total[o + 4];
    t0.x += a.x; t0.y += a.y; t0.z += a.z; t0.w += a.w;
    t1.x += b.x; t1.y += b.y; t1.z += b.z; t1.w += b.w;
    *(float4*)&total[o]     = t0;
    *(float4*)&total[o + 4] = t1;
    if (total2){
      *(float4*)&total2[o]     = t0;
      *(float4*)&total2[o + 4] = t1;
    }
  }
}

// ---------------- attention: one wave per node, L=17, H=4, dh=32; bf16 Q/K/V --------------
// K/V gathers iterate the 16 samples in ASCENDING order (softmax is order-invariant;
// pos tables indexed by the recovered original j). Concurrent waves sweep a shared
// sliding col-window -> per-XCD L2 captures the K/V gather instead of random misses.
__global__ __launch_bounds__(256) void attn_kernel(const ushort_t* __restrict__ QP,
    const ushort_t* __restrict__ KP, const ushort_t* __restrict__ VP,
    const int* __restrict__ samples,
    const float* __restrict__ posQ, const float* __restrict__ posK, const float* __restrict__ posV,
    ushort_t* __restrict__ O, int base, int cnt){
  int wid  = (blockIdx.x*blockDim.x + threadIdx.x) >> 6;
  int lane = threadIdx.x & 63;
  if (wid >= cnt) return;                       // wave-uniform exit
  int n = base + wid;
  const uint32* Q2 = (const uint32*)QP;
  const uint32* K2 = (const uint32*)KP;
  const uint32* V2 = (const uint32*)VP;
  const float2* pQ2 = (const float2*)posQ;
  const float2* pK2 = (const float2*)posK;
  const float2* pV2 = (const float2*)posV;
  float2 pq = pQ2[lane];
  uint32 qu = Q2[(size_t)n*64 + lane];
  float qx = bflo(qu) + pq.x, qy = bfhi(qu) + pq.y;
  int smp = (lane < KK) ? samples[(size_t)n*KK + lane] : 0;
  // rank of each lane's sample (strict total order via lane tie-break)
  int rank = 0;
  #pragma unroll
  for (int t = 0; t < KK; t++){
    int v = __shfl(smp, t, 64);
    rank += (v < smp) || (v == smp && t < lane);
  }
  float sc[17], vx[17], vy[17];
  #pragma unroll
  for (int t = 0; t < 17; t++){
    int row, j;
    if (t == 0){ row = n; j = 0; }
    else {
      unsigned long long mask = __ballot(lane < KK && rank == t-1);
      int src = __builtin_ctzll(mask);
      row = __shfl(smp, src, 64);
      j = src + 1;
    }
    uint32 ku = K2[(size_t)row*64 + lane];
    uint32 vu = V2[(size_t)row*64 + lane];
    float2 pk = pK2[j*64 + lane];
    float2 pv = pV2[j*64 + lane];
    float kx = bflo(ku) + pk.x, ky = bfhi(ku) + pk.y;
    vx[t] = bflo(vu) + pv.x; vy[t] = bfhi(vu) + pv.y;
    float p = qx*kx + qy*ky;              // head = lane>>4 (dims 2*lane, 2*lane+1)
    p += __shfl_xor(p, 1, 64);
    p += __shfl_xor(p, 2, 64);
    p += __shfl_xor(p, 4, 64);
    p += __shfl_xor(p, 8, 64);
    sc[t] = p * 0.17677669529663687f;     // 1/sqrt(32)
  }
  float m = sc[0];
  #pragma unroll
  for (int t=1;t<17;t++) m = fmaxf(m, sc[t]);
  float ssum = 0.f;
  #pragma unroll
  for (int t=0;t<17;t++){ sc[t] = __expf(sc[t]-m); ssum += sc[t]; }
  float inv = 1.f/ssum;
  float ox=0.f, oy=0.f;
  #pragma unroll
  for (int t=0;t<17;t++){ ox += sc[t]*vx[t]; oy += sc[t]*vy[t]; }
  ((uint32*)O)[(size_t)n*64 + lane] = pack2(ox*inv, oy*inv);
}

extern "C" void kernel_launch(void* const* d_in, const int* in_sizes, int n_in,
                              void* d_out, int out_size, void* d_ws, size_t ws_size,
                              hipStream_t stream){
  const int*   adj_rows = (const int*)d_in[0];
  const int*   adj_cols = (const int*)d_in[1];
  const float* adj_vals = (const float*)d_in[2];
  const int*   samples  = (const int*)d_in[3];
  const float* user_emb = (const float*)d_in[4];
  const float* item_emb = (const float*)d_in[5];
  const float* pos_emb  = (const float*)d_in[6];
  const float* u_in_w   = (const float*)d_in[7];
  const float* u_in_b   = (const float*)d_in[8];
  const float* u_out_w  = (const float*)d_in[9];
  const float* u_out_b  = (const float*)d_in[10];
  const float* i_in_w   = (const float*)d_in[11];
  const float* i_in_b   = (const float*)d_in[12];
  const float* i_out_w  = (const float*)d_in[13];
  const float* i_out_b  = (const float*)d_in[14];
  float* out = (float*)d_out;

  char* ws = (char*)d_ws;
  size_t off = 0;
  auto alloc = [&](size_t bytes)->char*{
    char* p = ws + off; off += (bytes + 255) & ~(size_t)255; return p;
  };
  ushort_t* tmp_bf  = (ushort_t*)alloc((size_t)NN*DD*2);
  ushort_t* e_bf    = (ushort_t*)alloc((size_t)NN*DD*2);
  ushort_t* Qb      = (ushort_t*)alloc((size_t)NN*DD*2);
  ushort_t* Ku      = (ushort_t*)alloc((size_t)NN*DD*2);
  ushort_t* Vu      = (ushort_t*)alloc((size_t)NN*DD*2);
  ushort_t* Ki      = (ushort_t*)alloc((size_t)NN*DD*2);
  ushort_t* Vi      = (ushort_t*)alloc((size_t)NN*DD*2);
  ushort_t* Ob      = (ushort_t*)alloc((size_t)NN*DD*2);
  uint2*    csr     = (uint2*)   alloc((size_t)EE*8);
  int*      cntG    = (int*)     alloc((size_t)(NB*NG)*4);
  int*      baseG   = (int*)     alloc((size_t)(NB*NG)*4);
  int*      row_ptr = (int*)     alloc((size_t)(NN+1)*4);
  int*      bsum    = (int*)     alloc(320*4);
  int*      bpre    = (int*)     alloc(320*4);
  float*    pt      = (float*)   alloc((size_t)8960*4);
  ushort_t* wbf     = (ushort_t*)alloc((size_t)131072*2);

  // Aliases (all stream-ordered, safe under graph replay):
  //  kv  (12.8MB) -> Ob  : Ob first written by attn, long after s4 consumed kv.
  //  kvC (25.6MB) -> Qb+Ku : both first written by gemm5, after sB3 consumed kvC.
  //  cntC/baseC (320KB ea) -> csr : csr first written by s4, after sA3 consumed baseC.
  uint2* kv  = (uint2*)Ob;
  uint4* kvC = (uint4*)Qb;
  int*   cntC  = (int*)csr;
  int*   baseC = (int*)csr + NB*NG;

  float* posK_u = pt;
  float* posV_u = pt + 17*128;
  float* posK_i = pt + 2*17*128;
  float* posV_i = pt + 3*17*128;
  float* posQ_u = pt + 4*17*128;
  float* posQ_i = pt + 4*17*128 + 128;

  ushort_t* wo_u = wbf + 6*16384;
  ushort_t* wo_i = wbf + 7*16384;

  init_e_total<<<NN*DD/4/256, 256, 0, stream>>>(user_emb, item_emb, e_bf, out);
  // ---- CSR build: col-bucket sort, then row sort (approx-stable => col order in rows) ----
  sA1_hist<<<NG, 256, 0, stream>>>(adj_cols, cntC);
  sum313<<<NB, 256, 0, stream>>>(cntC, bsum);
  scanb<<<1, 512, 0, stream>>>(bsum, bpre);
  scanE<<<NB, 256, 0, stream>>>(cntC, bpre, baseC);
  sA3_scatter<<<NG, 256, 0, stream>>>(adj_rows, adj_cols, adj_vals, baseC, kvC);
  sB1_hist<<<NG, 256, 0, stream>>>(kvC, cntG);
  sum313<<<NB, 256, 0, stream>>>(cntG, bsum);
  scanb<<<1, 512, 0, stream>>>(bsum, bpre);
  scanE<<<NB, 256, 0, stream>>>(cntG, bpre, baseG);
  sB3_scatter<<<NG, 256, 0, stream>>>(kvC, baseG, kv);
  s4_sort<<<NB, 256, 0, stream>>>(baseG, kv, row_ptr, csr);
  pos_proj<<<dim3(17,6), 128, 0, stream>>>(pos_emb, u_in_w, u_in_b, i_in_w, i_in_b, pt);
  cvt_weights<<<512, 256, 0, stream>>>(u_in_w, i_in_w, u_out_w, i_out_w, wbf);

  for (int it = 0; it < 2; it++){
    float* tot2 = (it == 1) ? (out + (size_t)NN*DD) : nullptr;
    spmm_kernel<<<NN/4, 256, 0, stream>>>(row_ptr, csr, e_bf, tmp_bf);
    gemm5<<<NN/64, 256, 0, stream>>>(tmp_bf, wbf, Qb, Ku, Vu, Ki, Vi);
    attn_kernel<<<USER_N/4, 256, 0, stream>>>(Qb, Ku, Vu, samples, posQ_u, posK_u, posV_u,
                                              Ob, 0, USER_N);
    attn_kernel<<<ITEM_N/4, 256, 0, stream>>>(Qb, Ki, Vi, samples, posQ_i, posK_i, posV_i,
                                              Ob, USER_N, ITEM_N);
    out_all<<<NN/64, 256, 0, stream>>>(Ob, wo_u, wo_i, u_out_b, i_out_b,
                                       tmp_bf, e_bf, out, tot2);
  }
}

// Round 4
// 751.324 us; speedup vs baseline: 1.4047x; 1.2313x over previous
//
#include <hip/hip_runtime.h>
#include <hip/hip_bf16.h>
#include <cstdint>
#include <cstddef>

#define USER_N 40000
#define ITEM_N 40000
#define NN     80000
#define DD     128
#define KK     16
#define EE     1600000

// counting-sort geometry: 313 buckets of 256 rows (313*256 = 80128), 256 edge-groups
#define NB    313
#define NG    256
#define EPG   (EE/NG)     // 6250
#define SCAP  5888        // LDS staging capacity per bucket (mean 5111, sigma ~71)

typedef __attribute__((ext_vector_type(8))) short bf16x8;
typedef __attribute__((ext_vector_type(4))) float f32x4;
typedef unsigned short ushort_t;
typedef unsigned int   uint32;

static __device__ __forceinline__ ushort_t f2bf(float x){
  __hip_bfloat16 h = __float2bfloat16(x);
  return *reinterpret_cast<ushort_t*>(&h);
}
static __device__ __forceinline__ float bflo(uint32 u){ return __uint_as_float(u << 16); }
static __device__ __forceinline__ float bfhi(uint32 u){ return __uint_as_float(u & 0xffff0000u); }
static __device__ __forceinline__ uint32 pack2(float a, float b){
  return (uint32)f2bf(a) | ((uint32)f2bf(b) << 16);
}

// ---------------- init: e_bf = bf16(concat(user,item)); total(d_out) = concat ----------------
__global__ void init_e_total(const float* __restrict__ user_emb, const float* __restrict__ item_emb,
                             ushort_t* __restrict__ e_bf, float* __restrict__ total){
  int idx = blockIdx.x*blockDim.x + threadIdx.x;           // float4 index
  const int n4 = NN*DD/4;
  if (idx >= n4) return;
  const int u4 = USER_N*DD/4;
  float4 v = (idx < u4) ? ((const float4*)user_emb)[idx] : ((const float4*)item_emb)[idx - u4];
  ((float4*)total)[idx] = v;
  ushort4 b; b.x = f2bf(v.x); b.y = f2bf(v.y); b.z = f2bf(v.z); b.w = f2bf(v.w);
  ((ushort4*)e_bf)[idx] = b;
}

// ---------------- weights -> bf16 ----------------
__global__ void cvt_weights(const float* __restrict__ u_in_w, const float* __restrict__ i_in_w,
                            const float* __restrict__ u_out_w, const float* __restrict__ i_out_w,
                            ushort_t* __restrict__ wbf){
  int i = blockIdx.x*256 + threadIdx.x;   // 512 blocks x 256 = 131072
  float v;
  if      (i < 49152)  v = u_in_w[i];
  else if (i < 98304)  v = i_in_w[i - 49152];
  else if (i < 114688) v = u_out_w[i - 98304];
  else                 v = i_out_w[i - 114688];
  wbf[i] = f2bf(v);
}

// ---------- CSR build: single-level row counting sort (col-pre-sort reverted: FETCH
// evidence r1 vs r3 showed identical spmm traffic -> per-XCD compulsory floor) ----------
__global__ __launch_bounds__(256) void s1_hist(const int* __restrict__ rows,
                                               int* __restrict__ cntG){
  __shared__ int h[NB];
  int g = blockIdx.x, tid = threadIdx.x;
  for (int b = tid; b < NB; b += 256) h[b] = 0;
  __syncthreads();
  int s = g*EPG;
  for (int i = s + tid; i < s + EPG; i += 256)
    atomicAdd(&h[rows[i] >> 8], 1);
  __syncthreads();
  for (int b = tid; b < NB; b += 256) cntG[b*NG + g] = h[b];
}

// S2a: per-256-chunk sums (313 blocks exactly cover 80128 entries)
__global__ void sum313(const int* __restrict__ in, int* __restrict__ bsum){
  __shared__ int s[256];
  s[threadIdx.x] = in[blockIdx.x*256 + threadIdx.x];
  __syncthreads();
  for (int o = 128; o > 0; o >>= 1){
    if (threadIdx.x < o) s[threadIdx.x] += s[threadIdx.x + o];
    __syncthreads();
  }
  if (threadIdx.x == 0) bsum[blockIdx.x] = s[0];
}

// S2b: exclusive scan of the 313 chunk sums
__global__ void scanb(const int* __restrict__ bsum, int* __restrict__ bpre){
  __shared__ int s[512];
  int v = (threadIdx.x < NB) ? bsum[threadIdx.x] : 0;
  s[threadIdx.x] = v;
  __syncthreads();
  for (int o = 1; o < 512; o <<= 1){
    int t = (threadIdx.x >= o) ? s[threadIdx.x - o] : 0;
    __syncthreads();
    s[threadIdx.x] += t;
    __syncthreads();
  }
  if (threadIdx.x < NB) bpre[threadIdx.x] = s[threadIdx.x] - v;
}

// S2c: per-element exclusive prefix
__global__ void scanE(const int* __restrict__ in, const int* __restrict__ bpre,
                      int* __restrict__ baseX){
  __shared__ int s[256];
  int i = blockIdx.x*256 + threadIdx.x;
  int v = in[i];
  s[threadIdx.x] = v;
  __syncthreads();
  for (int o = 1; o < 256; o <<= 1){
    int t = (threadIdx.x >= o) ? s[threadIdx.x - o] : 0;
    __syncthreads();
    s[threadIdx.x] += t;
    __syncthreads();
  }
  baseX[i] = bpre[blockIdx.x] + s[threadIdx.x] - v;
}

// S3: scatter edges into row-bucket-major order; block-private sequential regions.
// kv entry: x = (row&255)<<17 | col, y = val bits.
__global__ __launch_bounds__(256) void s3_scatter(const int* __restrict__ rows,
    const int* __restrict__ cols, const float* __restrict__ vals,
    const int* __restrict__ baseG, uint2* __restrict__ kv){
  __shared__ int cur[NB];
  int g = blockIdx.x, tid = threadIdx.x;
  for (int b = tid; b < NB; b += 256) cur[b] = baseG[b*NG + g];
  __syncthreads();
  int s = g*EPG;
  for (int i = s + tid; i < s + EPG; i += 256){
    int r = rows[i];
    int p = atomicAdd(&cur[r >> 8], 1);
    kv[p] = make_uint2(((uint32)(r & 255) << 17) | (uint32)cols[i], __float_as_uint(vals[i]));
  }
}

// S4: one block per row-bucket. Stage in LDS, histogram 256 rows, scan, emit row_ptr,
// scatter to final CSR slots (contiguous ~41KB per block).
__global__ __launch_bounds__(256) void s4_sort(const int* __restrict__ baseG,
    const uint2* __restrict__ kv, int* __restrict__ row_ptr, uint2* __restrict__ csr){
  __shared__ uint2 stage[SCAP];
  __shared__ int hist[256], sc[256], curs[256];
  int b = blockIdx.x, tid = threadIdx.x;
  int start = baseG[b*NG];
  int end   = (b == NB-1) ? EE : baseG[(b+1)*NG];
  int cnt = end - start;
  hist[tid] = 0;
  __syncthreads();
  for (int i = tid; i < cnt; i += 256){
    uint2 e = kv[start + i];
    if (i < SCAP) stage[i] = e;
    atomicAdd(&hist[e.x >> 17], 1);
  }
  __syncthreads();
  int v = hist[tid];
  sc[tid] = v;
  __syncthreads();
  for (int o = 1; o < 256; o <<= 1){
    int t = (tid >= o) ? sc[tid - o] : 0;
    __syncthreads();
    sc[tid] += t;
    __syncthreads();
  }
  int ex = sc[tid] - v;          // exclusive prefix within bucket
  curs[tid] = ex;
  int grow = b*256 + tid;
  if (grow <= NN) row_ptr[grow] = start + ex;   // covers row_ptr[NN] (b=312, tid=128)
  __syncthreads();
  for (int i = tid; i < cnt; i += 256){
    uint2 e = (i < SCAP) ? stage[i] : kv[start + i];
    int r = (int)(e.x >> 17);
    int p = atomicAdd(&curs[r], 1);
    csr[start + p] = make_uint2(e.x & 0x1FFFFu, e.y);
  }
}

// ---------------- SpMM: one wave per row; 8-deep pipelined gathers ----------------------
// Latency-bound fix: issue 8 independent csr loads then 8 independent 256B gathers before
// consuming -> 4x outstanding bytes per wave vs the old unroll-2 dependent chain.
__global__ __launch_bounds__(256) void spmm_kernel(const int* __restrict__ row_ptr,
    const uint2* __restrict__ csr, const ushort_t* __restrict__ e_bf,
    ushort_t* __restrict__ tmp_bf){
  int wid  = (blockIdx.x*blockDim.x + threadIdx.x) >> 6;
  int lane = threadIdx.x & 63;
  if (wid >= NN) return;
  int s = row_ptr[wid], t = row_ptr[wid+1];
  const uint32* E = (const uint32*)e_bf;   // 2 bf16 per uint
  float ax = 0.f, ay = 0.f;
  int e = s;
  for (; e + 8 <= t; e += 8){
    uint2 c[8];
    #pragma unroll
    for (int k=0;k<8;k++) c[k] = csr[e+k];
    uint32 x[8];
    #pragma unroll
    for (int k=0;k<8;k++) x[k] = E[(size_t)c[k].x*64 + lane];
    #pragma unroll
    for (int k=0;k<8;k++){
      float v = __uint_as_float(c[k].y);
      ax += v*bflo(x[k]); ay += v*bfhi(x[k]);
    }
  }
  for (; e + 4 <= t; e += 4){
    uint2 c[4];
    #pragma unroll
    for (int k=0;k<4;k++) c[k] = csr[e+k];
    uint32 x[4];
    #pragma unroll
    for (int k=0;k<4;k++) x[k] = E[(size_t)c[k].x*64 + lane];
    #pragma unroll
    for (int k=0;k<4;k++){
      float v = __uint_as_float(c[k].y);
      ax += v*bflo(x[k]); ay += v*bfhi(x[k]);
    }
  }
  for (; e < t; e++){
    uint2 c0 = csr[e];
    float v0 = __uint_as_float(c0.y);
    uint32 x0 = E[(size_t)c0.x*64 + lane];
    ax += v0*bflo(x0); ay += v0*bfhi(x0);
  }
  ((uint32*)tmp_bf)[(size_t)wid*64 + lane] = pack2(ax, ay);
}

// ---------------- pos tables (fp32): pos_emb @ W.T + b for Q/K/V, u/i ----------------
__global__ void pos_proj(const float* __restrict__ pos_emb,
                         const float* __restrict__ u_in_w, const float* __restrict__ u_in_b,
                         const float* __restrict__ i_in_w, const float* __restrict__ i_in_b,
                         float* __restrict__ pt){
  int j = blockIdx.x;      // 0..16
  int m = blockIdx.y;      // 0..5
  int d = threadIdx.x;     // 0..127
  if (m >= 4 && j > 0) return;
  const float* w; const float* b; float* out; int roff;
  switch (m){
    case 0: w=u_in_w; b=u_in_b; roff=128; out=pt + j*128;            break; // posK_u
    case 1: w=u_in_w; b=u_in_b; roff=256; out=pt + 17*128 + j*128;   break; // posV_u
    case 2: w=i_in_w; b=i_in_b; roff=128; out=pt + 2*17*128 + j*128; break; // posK_i
    case 3: w=i_in_w; b=i_in_b; roff=256; out=pt + 3*17*128 + j*128; break; // posV_i
    case 4: w=u_in_w; b=u_in_b; roff=0;   out=pt + 4*17*128;         break; // posQ_u
    default:w=i_in_w; b=i_in_b; roff=0;   out=pt + 4*17*128 + 128;   break; // posQ_i
  }
  int row = roff + d;
  float acc = b[row];
  for (int c = 0; c < DD; c++) acc += pos_emb[j*DD + c] * w[row*DD + c];
  out[d] = acc;
}

// ---- wave-private LDS transpose of a 16x128 MFMA C-tile, then coalesced bf16 stores ----
static __device__ __forceinline__ void tile_store_bf16(float* __restrict__ T,
    const f32x4* acc, ushort_t* __restrict__ dst, int row0, int jg, int lr, int l){
  #pragma unroll
  for (int r=0;r<4;r++){
    int row = jg*4 + r;
    #pragma unroll
    for (int ct=0;ct<8;ct++) T[row*132 + ct*16 + lr] = acc[ct][r];
  }
  // wave-private: no barrier needed, compiler orders ds via lgkmcnt
  #pragma unroll
  for (int i=0;i<4;i++){
    int row = l & 15;
    int p = (l >> 4) + 4*i;          // 16B-pair index 0..15 (8 cols each)
    const float* src = &T[row*132 + p*8];
    float4 a = *(const float4*)src;
    float4 b = *(const float4*)(src + 4);
    uint4 w = make_uint4(pack2(a.x,a.y), pack2(a.z,a.w), pack2(b.x,b.y), pack2(b.z,b.w));
    *(uint4*)&dst[(size_t)(row0 + row)*128 + p*8] = w;
  }
}

// ------- 5-in-1 GEMM: 1250 blocks; A-frags register-resident, reused across 5 weight
// matrices; weights staged global->LDS in 16KB halves (XOR-swizzled). ---------------------
__global__ __launch_bounds__(256,3) void gemm5(const ushort_t* __restrict__ A,
    const ushort_t* __restrict__ wbf, ushort_t* __restrict__ Qb,
    ushort_t* __restrict__ Ku, ushort_t* __restrict__ Vu,
    ushort_t* __restrict__ Ki, ushort_t* __restrict__ Vi){
  __shared__ ushort_t wlds[8192];          // 16KB: one half-matrix (64 rows x 128 k)
  __shared__ float   tlds[4][16*132];      // 33.8KB transpose buffers (wave-private)
  int tid = threadIdx.x;
  int wvi = tid >> 6, l = tid & 63, lr = l & 15, jg = l >> 4;
  int row0 = blockIdx.x*64 + wvi*16;
  bool isU = (blockIdx.x*64) < USER_N;     // block-uniform (64 | 40000)

  // A fragments: 16 rows x 128 k in registers, reused for all 5 matrices
  const bf16x8* Av = (const bf16x8*)A;
  bf16x8 aFrag[4];
  #pragma unroll
  for (int kc = 0; kc < 4; kc++)
    aFrag[kc] = Av[(size_t)(row0 + lr)*16 + kc*4 + jg];

  const ushort_t* Wm[5];
  ushort_t* Dm[5];
  Wm[0] = isU ? wbf : (wbf + 3*16384);  Dm[0] = Qb;   // wq_u / wq_i
  Wm[1] = wbf + 16384;                  Dm[1] = Ku;   // wk_u
  Wm[2] = wbf + 2*16384;                Dm[2] = Vu;   // wv_u
  Wm[3] = wbf + 4*16384;                Dm[3] = Ki;   // wk_i
  Wm[4] = wbf + 5*16384;                Dm[4] = Vi;   // wv_i

  #pragma unroll
  for (int m = 0; m < 5; m++){
    f32x4 acc[8];
    #pragma unroll
    for (int c=0;c<8;c++) acc[c]=(f32x4){0,0,0,0};
    #pragma unroll
    for (int h = 0; h < 2; h++){
      __syncthreads();                               // prev readers done
      // stage half h: rows 64h..64h+63 of W (16KB), swizzled byte ^= (row&7)<<4
      const uint4* src = (const uint4*)(Wm[m] + h*8192);
      #pragma unroll
      for (int r = 0; r < 4; r++){
        int u = r*256 + tid;                         // 16B unit 0..1023
        uint32 sw = ((uint32)u*16) ^ (((uint32)(u>>4)&7u)<<4);
        *(uint4*)((char*)wlds + sw) = src[u];
      }
      __syncthreads();                               // staging visible
      #pragma unroll
      for (int kc = 0; kc < 4; kc++){
        #pragma unroll
        for (int ct = 0; ct < 4; ct++){
          uint32 rowh = (uint32)(ct*16 + lr);
          uint32 byte = (rowh*256u + (uint32)(kc*4 + jg)*16u) ^ ((rowh&7u)<<4);
          bf16x8 b = *(const bf16x8*)((const char*)wlds + byte);
          acc[h*4+ct] = __builtin_amdgcn_mfma_f32_16x16x32_bf16(aFrag[kc], b, acc[h*4+ct], 0, 0, 0);
        }
      }
    }
    tile_store_bf16(tlds[wvi], acc, Dm[m], row0, jg, lr, l);
  }
}

// ---------------- out-projection (wave-uniform weight select) + coalesced epilogue -------
__global__ __launch_bounds__(256,4) void out_all(const ushort_t* __restrict__ A,
    const ushort_t* __restrict__ wo_u, const ushort_t* __restrict__ wo_i,
    const float* __restrict__ bu, const float* __restrict__ bi_,
    const ushort_t* __restrict__ resid_bf, ushort_t* __restrict__ e_bf,
    float* __restrict__ total, float* __restrict__ total2){
  __shared__ float lds[4][16*132];
  int tid = threadIdx.x;
  int wvi = tid >> 6, l = tid & 63, lr = l & 15, jg = l >> 4;
  int row0 = blockIdx.x*64 + wvi*16;
  bool isU = row0 < USER_N;
  const bf16x8* Av = (const bf16x8*)A;
  const bf16x8* Bw = (const bf16x8*)(isU ? wo_u : wo_i);
  const float*  bias = isU ? bu : bi_;
  f32x4 acc[8];
  #pragma unroll
  for (int c=0;c<8;c++) acc[c]=(f32x4){0,0,0,0};
  #pragma unroll
  for (int kc = 0; kc < 4; kc++){
    int ko = kc*4 + jg;
    bf16x8 a = Av[(size_t)(row0 + lr)*16 + ko];
    #pragma unroll
    for (int ct=0;ct<8;ct++)
      acc[ct] = __builtin_amdgcn_mfma_f32_16x16x32_bf16(a, Bw[(size_t)(ct*16+lr)*16 + ko], acc[ct], 0, 0, 0);
  }
  float* T = lds[wvi];
  #pragma unroll
  for (int r=0;r<4;r++){
    int row = jg*4 + r;
    #pragma unroll
    for (int ct=0;ct<8;ct++) T[row*132 + ct*16 + lr] = acc[ct][r];
  }
  #pragma unroll
  for (int i=0;i<4;i++){
    int row = l & 15;
    int p = (l >> 4) + 4*i;
    int grow = row0 + row;
    size_t o = (size_t)grow*128 + p*8;
    const float* src = &T[row*132 + p*8];
    float4 a = *(const float4*)src;
    float4 b = *(const float4*)(src + 4);
    float4 ba = *(const float4*)&bias[p*8];
    float4 bb = *(const float4*)&bias[p*8 + 4];
    uint4 rr = *(const uint4*)&resid_bf[o];
    a.x += ba.x + bflo(rr.x); a.y += ba.y + bfhi(rr.x);
    a.z += ba.z + bflo(rr.y); a.w += ba.w + bfhi(rr.y);
    b.x += bb.x + bflo(rr.z); b.y += bb.y + bfhi(rr.z);
    b.z += bb.z + bflo(rr.w); b.w += bb.w + bfhi(rr.w);
    *(uint4*)&e_bf[o] = make_uint4(pack2(a.x,a.y), pack2(a.z,a.w), pack2(b.x,b.y), pack2(b.z,b.w));
    float4 t0 = *(const float4*)&total[o];
    float4 t1 = *(const float4*)&total[o + 4];
    t0.x += a.x; t0.y += a.y; t0.z += a.z; t0.w += a.w;
    t1.x += b.x; t1.y += b.y; t1.z += b.z; t1.w += b.w;
    *(float4*)&total[o]     = t0;
    *(float4*)&total[o + 4] = t1;
    if (total2){
      *(float4*)&total2[o]     = t0;
      *(float4*)&total2[o + 4] = t1;
    }
  }
}

// ---------------- attention: one wave per node, L=17, H=4, dh=32; bf16 Q/K/V --------------
// Latency fix: all 34 K/V gathers are issued BEFORE any score math (fully unrolled,
// static register arrays) -> 17x the outstanding loads of the old serialized loop.
__global__ __launch_bounds__(256) void attn_kernel(const ushort_t* __restrict__ QP,
    const ushort_t* __restrict__ KP, const ushort_t* __restrict__ VP,
    const int* __restrict__ samples,
    const float* __restrict__ posQ, const float* __restrict__ posK, const float* __restrict__ posV,
    ushort_t* __restrict__ O, int base, int cnt){
  int wid  = (blockIdx.x*blockDim.x + threadIdx.x) >> 6;
  int lane = threadIdx.x & 63;
  if (wid >= cnt) return;                       // wave-uniform exit
  int n = base + wid;
  const uint32* Q2 = (const uint32*)QP;
  const uint32* K2 = (const uint32*)KP;
  const uint32* V2 = (const uint32*)VP;
  const float2* pQ2 = (const float2*)posQ;
  const float2* pK2 = (const float2*)posK;
  const float2* pV2 = (const float2*)posV;
  int smp = (lane < KK) ? samples[(size_t)n*KK + lane] : 0;
  // issue all K/V gathers up front (independent; huge MLP)
  uint32 ku[17], vu[17];
  #pragma unroll
  for (int j = 0; j < 17; j++){
    int row = (j==0) ? n : __shfl(smp, j-1, 64);
    ku[j] = K2[(size_t)row*64 + lane];
    vu[j] = V2[(size_t)row*64 + lane];
  }
  float2 pq = pQ2[lane];
  uint32 qu = Q2[(size_t)n*64 + lane];
  float qx = bflo(qu) + pq.x, qy = bfhi(qu) + pq.y;
  float sc[17];
  #pragma unroll
  for (int j = 0; j < 17; j++){
    float2 pk = pK2[j*64 + lane];
    float kx = bflo(ku[j]) + pk.x, ky = bfhi(ku[j]) + pk.y;
    float p = qx*kx + qy*ky;              // head = lane>>4 (dims 2*lane, 2*lane+1)
    p += __shfl_xor(p, 1, 64);
    p += __shfl_xor(p, 2, 64);
    p += __shfl_xor(p, 4, 64);
    p += __shfl_xor(p, 8, 64);
    sc[j] = p * 0.17677669529663687f;     // 1/sqrt(32)
  }
  float m = sc[0];
  #pragma unroll
  for (int j=1;j<17;j++) m = fmaxf(m, sc[j]);
  float ssum = 0.f;
  #pragma unroll
  for (int j=0;j<17;j++){ sc[j] = __expf(sc[j]-m); ssum += sc[j]; }
  float inv = 1.f/ssum;
  float ox=0.f, oy=0.f;
  #pragma unroll
  for (int j=0;j<17;j++){
    float2 pv = pV2[j*64 + lane];
    ox += sc[j]*(bflo(vu[j]) + pv.x);
    oy += sc[j]*(bfhi(vu[j]) + pv.y);
  }
  ((uint32*)O)[(size_t)n*64 + lane] = pack2(ox*inv, oy*inv);
}

extern "C" void kernel_launch(void* const* d_in, const int* in_sizes, int n_in,
                              void* d_out, int out_size, void* d_ws, size_t ws_size,
                              hipStream_t stream){
  const int*   adj_rows = (const int*)d_in[0];
  const int*   adj_cols = (const int*)d_in[1];
  const float* adj_vals = (const float*)d_in[2];
  const int*   samples  = (const int*)d_in[3];
  const float* user_emb = (const float*)d_in[4];
  const float* item_emb = (const float*)d_in[5];
  const float* pos_emb  = (const float*)d_in[6];
  const float* u_in_w   = (const float*)d_in[7];
  const float* u_in_b   = (const float*)d_in[8];
  const float* u_out_w  = (const float*)d_in[9];
  const float* u_out_b  = (const float*)d_in[10];
  const float* i_in_w   = (const float*)d_in[11];
  const float* i_in_b   = (const float*)d_in[12];
  const float* i_out_w  = (const float*)d_in[13];
  const float* i_out_b  = (const float*)d_in[14];
  float* out = (float*)d_out;

  char* ws = (char*)d_ws;
  size_t off = 0;
  auto alloc = [&](size_t bytes)->char*{
    char* p = ws + off; off += (bytes + 255) & ~(size_t)255; return p;
  };
  ushort_t* tmp_bf  = (ushort_t*)alloc((size_t)NN*DD*2);
  ushort_t* e_bf    = (ushort_t*)alloc((size_t)NN*DD*2);
  ushort_t* Qb      = (ushort_t*)alloc((size_t)NN*DD*2);
  ushort_t* Ku      = (ushort_t*)alloc((size_t)NN*DD*2);
  ushort_t* Vu      = (ushort_t*)alloc((size_t)NN*DD*2);
  ushort_t* Ki      = (ushort_t*)alloc((size_t)NN*DD*2);
  ushort_t* Vi      = (ushort_t*)alloc((size_t)NN*DD*2);
  ushort_t* Ob      = (ushort_t*)alloc((size_t)NN*DD*2);
  uint2*    csr     = (uint2*)   alloc((size_t)EE*8);
  int*      cntG    = (int*)     alloc((size_t)(NB*NG)*4);
  int*      baseG   = (int*)     alloc((size_t)(NB*NG)*4);
  int*      row_ptr = (int*)     alloc((size_t)(NN+1)*4);
  int*      bsum    = (int*)     alloc(320*4);
  int*      bpre    = (int*)     alloc(320*4);
  float*    pt      = (float*)   alloc((size_t)8960*4);
  ushort_t* wbf     = (ushort_t*)alloc((size_t)131072*2);

  // kv (12.8MB) aliases Ob: Ob first written by attn, long after s4 consumed kv.
  uint2* kv = (uint2*)Ob;

  float* posK_u = pt;
  float* posV_u = pt + 17*128;
  float* posK_i = pt + 2*17*128;
  float* posV_i = pt + 3*17*128;
  float* posQ_u = pt + 4*17*128;
  float* posQ_i = pt + 4*17*128 + 128;

  ushort_t* wo_u = wbf + 6*16384;
  ushort_t* wo_i = wbf + 7*16384;

  init_e_total<<<NN*DD/4/256, 256, 0, stream>>>(user_emb, item_emb, e_bf, out);
  // ---- CSR build: single-level row counting sort ----
  s1_hist<<<NG, 256, 0, stream>>>(adj_rows, cntG);
  sum313<<<NB, 256, 0, stream>>>(cntG, bsum);
  scanb<<<1, 512, 0, stream>>>(bsum, bpre);
  scanE<<<NB, 256, 0, stream>>>(cntG, bpre, baseG);
  s3_scatter<<<NG, 256, 0, stream>>>(adj_rows, adj_cols, adj_vals, baseG, kv);
  s4_sort<<<NB, 256, 0, stream>>>(baseG, kv, row_ptr, csr);
  pos_proj<<<dim3(17,6), 128, 0, stream>>>(pos_emb, u_in_w, u_in_b, i_in_w, i_in_b, pt);
  cvt_weights<<<512, 256, 0, stream>>>(u_in_w, i_in_w, u_out_w, i_out_w, wbf);

  for (int it = 0; it < 2; it++){
    float* tot2 = (it == 1) ? (out + (size_t)NN*DD) : nullptr;
    spmm_kernel<<<NN/4, 256, 0, stream>>>(row_ptr, csr, e_bf, tmp_bf);
    gemm5<<<NN/64, 256, 0, stream>>>(tmp_bf, wbf, Qb, Ku, Vu, Ki, Vi);
    attn_kernel<<<USER_N/4, 256, 0, stream>>>(Qb, Ku, Vu, samples, posQ_u, posK_u, posV_u,
                                              Ob, 0, USER_N);
    attn_kernel<<<ITEM_N/4, 256, 0, stream>>>(Qb, Ki, Vi, samples, posQ_i, posK_i, posV_i,
                                              Ob, USER_N, ITEM_N);
    out_all<<<NN/64, 256, 0, stream>>>(Ob, wo_u, wo_i, u_out_b, i_out_b,
                                       tmp_bf, e_bf, out, tot2);
  }
}

// Round 5
// 732.135 us; speedup vs baseline: 1.4415x; 1.0262x over previous
//
#include <hip/hip_runtime.h>
#include <hip/hip_bf16.h>
#include <cstdint>
#include <cstddef>

#define USER_N 40000
#define ITEM_N 40000
#define NN     80000
#define DD     128
#define KK     16
#define EE     1600000

// counting-sort geometry: 313 buckets of 256 rows (313*256 = 80128), 256 edge-groups
#define NB    313
#define NG    256
#define EPG   (EE/NG)     // 6250
#define SCAP  5888        // LDS staging capacity per bucket (mean 5111, sigma ~71)

typedef __attribute__((ext_vector_type(8))) short bf16x8;
typedef __attribute__((ext_vector_type(4))) float f32x4;
typedef unsigned short ushort_t;
typedef unsigned int   uint32;

static __device__ __forceinline__ ushort_t f2bf(float x){
  __hip_bfloat16 h = __float2bfloat16(x);
  return *reinterpret_cast<ushort_t*>(&h);
}
static __device__ __forceinline__ float bflo(uint32 u){ return __uint_as_float(u << 16); }
static __device__ __forceinline__ float bfhi(uint32 u){ return __uint_as_float(u & 0xffff0000u); }
static __device__ __forceinline__ uint32 pack2(float a, float b){
  return (uint32)f2bf(a) | ((uint32)f2bf(b) << 16);
}

// ---------------- init: e_bf = bf16(concat(user,item)); total(d_out) = concat ----------------
__global__ void init_e_total(const float* __restrict__ user_emb, const float* __restrict__ item_emb,
                             ushort_t* __restrict__ e_bf, float* __restrict__ total){
  int idx = blockIdx.x*blockDim.x + threadIdx.x;           // float4 index
  const int n4 = NN*DD/4;
  if (idx >= n4) return;
  const int u4 = USER_N*DD/4;
  float4 v = (idx < u4) ? ((const float4*)user_emb)[idx] : ((const float4*)item_emb)[idx - u4];
  ((float4*)total)[idx] = v;
  ushort4 b; b.x = f2bf(v.x); b.y = f2bf(v.y); b.z = f2bf(v.z); b.w = f2bf(v.w);
  ((ushort4*)e_bf)[idx] = b;
}

// ---------------- weights -> bf16 ----------------
__global__ void cvt_weights(const float* __restrict__ u_in_w, const float* __restrict__ i_in_w,
                            const float* __restrict__ u_out_w, const float* __restrict__ i_out_w,
                            ushort_t* __restrict__ wbf){
  int i = blockIdx.x*256 + threadIdx.x;   // 512 blocks x 256 = 131072
  float v;
  if      (i < 49152)  v = u_in_w[i];
  else if (i < 98304)  v = i_in_w[i - 49152];
  else if (i < 114688) v = u_out_w[i - 98304];
  else                 v = i_out_w[i - 114688];
  wbf[i] = f2bf(v);
}

// ---------- CSR build: single-level row counting sort ----------
__global__ __launch_bounds__(256) void s1_hist(const int* __restrict__ rows,
                                               int* __restrict__ cntG){
  __shared__ int h[NB];
  int g = blockIdx.x, tid = threadIdx.x;
  for (int b = tid; b < NB; b += 256) h[b] = 0;
  __syncthreads();
  int s = g*EPG;
  for (int i = s + tid; i < s + EPG; i += 256)
    atomicAdd(&h[rows[i] >> 8], 1);
  __syncthreads();
  for (int b = tid; b < NB; b += 256) cntG[b*NG + g] = h[b];
}

// S2a: per-256-chunk sums (313 blocks exactly cover 80128 entries)
__global__ void sum313(const int* __restrict__ in, int* __restrict__ bsum){
  __shared__ int s[256];
  s[threadIdx.x] = in[blockIdx.x*256 + threadIdx.x];
  __syncthreads();
  for (int o = 128; o > 0; o >>= 1){
    if (threadIdx.x < o) s[threadIdx.x] += s[threadIdx.x + o];
    __syncthreads();
  }
  if (threadIdx.x == 0) bsum[blockIdx.x] = s[0];
}

// S2b: exclusive scan of the 313 chunk sums
__global__ void scanb(const int* __restrict__ bsum, int* __restrict__ bpre){
  __shared__ int s[512];
  int v = (threadIdx.x < NB) ? bsum[threadIdx.x] : 0;
  s[threadIdx.x] = v;
  __syncthreads();
  for (int o = 1; o < 512; o <<= 1){
    int t = (threadIdx.x >= o) ? s[threadIdx.x - o] : 0;
    __syncthreads();
    s[threadIdx.x] += t;
    __syncthreads();
  }
  if (threadIdx.x < NB) bpre[threadIdx.x] = s[threadIdx.x] - v;
}

// S2c: per-element exclusive prefix
__global__ void scanE(const int* __restrict__ in, const int* __restrict__ bpre,
                      int* __restrict__ baseX){
  __shared__ int s[256];
  int i = blockIdx.x*256 + threadIdx.x;
  int v = in[i];
  s[threadIdx.x] = v;
  __syncthreads();
  for (int o = 1; o < 256; o <<= 1){
    int t = (threadIdx.x >= o) ? s[threadIdx.x - o] : 0;
    __syncthreads();
    s[threadIdx.x] += t;
    __syncthreads();
  }
  baseX[i] = bpre[blockIdx.x] + s[threadIdx.x] - v;
}

// S3: scatter edges into row-bucket-major order; block-private sequential regions.
// kv entry: x = (row&255)<<17 | col, y = val bits.
__global__ __launch_bounds__(256) void s3_scatter(const int* __restrict__ rows,
    const int* __restrict__ cols, const float* __restrict__ vals,
    const int* __restrict__ baseG, uint2* __restrict__ kv){
  __shared__ int cur[NB];
  int g = blockIdx.x, tid = threadIdx.x;
  for (int b = tid; b < NB; b += 256) cur[b] = baseG[b*NG + g];
  __syncthreads();
  int s = g*EPG;
  for (int i = s + tid; i < s + EPG; i += 256){
    int r = rows[i];
    int p = atomicAdd(&cur[r >> 8], 1);
    kv[p] = make_uint2(((uint32)(r & 255) << 17) | (uint32)cols[i], __float_as_uint(vals[i]));
  }
}

// S4: one block per row-bucket. Stage in LDS, histogram 256 rows, scan, emit row_ptr,
// scatter to final CSR slots (contiguous ~41KB per block).
__global__ __launch_bounds__(256) void s4_sort(const int* __restrict__ baseG,
    const uint2* __restrict__ kv, int* __restrict__ row_ptr, uint2* __restrict__ csr){
  __shared__ uint2 stage[SCAP];
  __shared__ int hist[256], sc[256], curs[256];
  int b = blockIdx.x, tid = threadIdx.x;
  int start = baseG[b*NG];
  int end   = (b == NB-1) ? EE : baseG[(b+1)*NG];
  int cnt = end - start;
  hist[tid] = 0;
  __syncthreads();
  for (int i = tid; i < cnt; i += 256){
    uint2 e = kv[start + i];
    if (i < SCAP) stage[i] = e;
    atomicAdd(&hist[e.x >> 17], 1);
  }
  __syncthreads();
  int v = hist[tid];
  sc[tid] = v;
  __syncthreads();
  for (int o = 1; o < 256; o <<= 1){
    int t = (tid >= o) ? sc[tid - o] : 0;
    __syncthreads();
    sc[tid] += t;
    __syncthreads();
  }
  int ex = sc[tid] - v;          // exclusive prefix within bucket
  curs[tid] = ex;
  int grow = b*256 + tid;
  if (grow <= NN) row_ptr[grow] = start + ex;   // covers row_ptr[NN] (b=312, tid=128)
  __syncthreads();
  for (int i = tid; i < cnt; i += 256){
    uint2 e = (i < SCAP) ? stage[i] : kv[start + i];
    int r = (int)(e.x >> 17);
    int p = atomicAdd(&curs[r], 1);
    csr[start + p] = make_uint2(e.x & 0x1FFFFu, e.y);
  }
}

// ---------------- SpMM: one wave per row; 8-deep pipelined gathers ----------------------
__global__ __launch_bounds__(256) void spmm_kernel(const int* __restrict__ row_ptr,
    const uint2* __restrict__ csr, const ushort_t* __restrict__ e_bf,
    ushort_t* __restrict__ tmp_bf){
  int wid  = (blockIdx.x*blockDim.x + threadIdx.x) >> 6;
  int lane = threadIdx.x & 63;
  if (wid >= NN) return;
  int s = row_ptr[wid], t = row_ptr[wid+1];
  const uint32* E = (const uint32*)e_bf;   // 2 bf16 per uint
  float ax = 0.f, ay = 0.f;
  int e = s;
  for (; e + 8 <= t; e += 8){
    uint2 c[8];
    #pragma unroll
    for (int k=0;k<8;k++) c[k] = csr[e+k];
    uint32 x[8];
    #pragma unroll
    for (int k=0;k<8;k++) x[k] = E[(size_t)c[k].x*64 + lane];
    #pragma unroll
    for (int k=0;k<8;k++){
      float v = __uint_as_float(c[k].y);
      ax += v*bflo(x[k]); ay += v*bfhi(x[k]);
    }
  }
  for (; e + 4 <= t; e += 4){
    uint2 c[4];
    #pragma unroll
    for (int k=0;k<4;k++) c[k] = csr[e+k];
    uint32 x[4];
    #pragma unroll
    for (int k=0;k<4;k++) x[k] = E[(size_t)c[k].x*64 + lane];
    #pragma unroll
    for (int k=0;k<4;k++){
      float v = __uint_as_float(c[k].y);
      ax += v*bflo(x[k]); ay += v*bfhi(x[k]);
    }
  }
  for (; e < t; e++){
    uint2 c0 = csr[e];
    float v0 = __uint_as_float(c0.y);
    uint32 x0 = E[(size_t)c0.x*64 + lane];
    ax += v0*bflo(x0); ay += v0*bfhi(x0);
  }
  ((uint32*)tmp_bf)[(size_t)wid*64 + lane] = pack2(ax, ay);
}

// ---------------- pos tables (fp32): pos_emb @ W.T + b for Q/K/V, u/i ----------------
__global__ void pos_proj(const float* __restrict__ pos_emb,
                         const float* __restrict__ u_in_w, const float* __restrict__ u_in_b,
                         const float* __restrict__ i_in_w, const float* __restrict__ i_in_b,
                         float* __restrict__ pt){
  int j = blockIdx.x;      // 0..16
  int m = blockIdx.y;      // 0..5
  int d = threadIdx.x;     // 0..127
  if (m >= 4 && j > 0) return;
  const float* w; const float* b; float* out; int roff;
  switch (m){
    case 0: w=u_in_w; b=u_in_b; roff=128; out=pt + j*128;            break; // posK_u
    case 1: w=u_in_w; b=u_in_b; roff=256; out=pt + 17*128 + j*128;   break; // posV_u
    case 2: w=i_in_w; b=i_in_b; roff=128; out=pt + 2*17*128 + j*128; break; // posK_i
    case 3: w=i_in_w; b=i_in_b; roff=256; out=pt + 3*17*128 + j*128; break; // posV_i
    case 4: w=u_in_w; b=u_in_b; roff=0;   out=pt + 4*17*128;         break; // posQ_u
    default:w=i_in_w; b=i_in_b; roff=0;   out=pt + 4*17*128 + 128;   break; // posQ_i
  }
  int row = roff + d;
  float acc = b[row];
  for (int c = 0; c < DD; c++) acc += pos_emb[j*DD + c] * w[row*DD + c];
  out[d] = acc;
}

// ---- wave-private LDS transpose of a 16x128 MFMA C-tile, then coalesced bf16 stores ----
static __device__ __forceinline__ void tile_store_bf16(float* __restrict__ T,
    const f32x4* acc, ushort_t* __restrict__ dst, int row0, int jg, int lr, int l){
  #pragma unroll
  for (int r=0;r<4;r++){
    int row = jg*4 + r;
    #pragma unroll
    for (int ct=0;ct<8;ct++) T[row*132 + ct*16 + lr] = acc[ct][r];
  }
  // wave-private: no barrier needed, compiler orders ds via lgkmcnt
  #pragma unroll
  for (int i=0;i<4;i++){
    int row = l & 15;
    int p = (l >> 4) + 4*i;          // 16B-pair index 0..15 (8 cols each)
    const float* src = &T[row*132 + p*8];
    float4 a = *(const float4*)src;
    float4 b = *(const float4*)(src + 4);
    uint4 w = make_uint4(pack2(a.x,a.y), pack2(a.z,a.w), pack2(b.x,b.y), pack2(b.z,b.w));
    *(uint4*)&dst[(size_t)(row0 + row)*128 + p*8] = w;
  }
}

// ------- 5-in-1 GEMM: 1250 blocks; A-frags register-resident, reused across 5 weight
// matrices; weights staged global->LDS in 16KB halves (XOR-swizzled). ---------------------
__global__ __launch_bounds__(256,3) void gemm5(const ushort_t* __restrict__ A,
    const ushort_t* __restrict__ wbf, ushort_t* __restrict__ Qb,
    ushort_t* __restrict__ Ku, ushort_t* __restrict__ Vu,
    ushort_t* __restrict__ Ki, ushort_t* __restrict__ Vi){
  __shared__ ushort_t wlds[8192];          // 16KB: one half-matrix (64 rows x 128 k)
  __shared__ float   tlds[4][16*132];      // 33.8KB transpose buffers (wave-private)
  int tid = threadIdx.x;
  int wvi = tid >> 6, l = tid & 63, lr = l & 15, jg = l >> 4;
  int row0 = blockIdx.x*64 + wvi*16;
  bool isU = (blockIdx.x*64) < USER_N;     // block-uniform (64 | 40000)

  // A fragments: 16 rows x 128 k in registers, reused for all 5 matrices
  const bf16x8* Av = (const bf16x8*)A;
  bf16x8 aFrag[4];
  #pragma unroll
  for (int kc = 0; kc < 4; kc++)
    aFrag[kc] = Av[(size_t)(row0 + lr)*16 + kc*4 + jg];

  const ushort_t* Wm[5];
  ushort_t* Dm[5];
  Wm[0] = isU ? wbf : (wbf + 3*16384);  Dm[0] = Qb;   // wq_u / wq_i
  Wm[1] = wbf + 16384;                  Dm[1] = Ku;   // wk_u
  Wm[2] = wbf + 2*16384;                Dm[2] = Vu;   // wv_u
  Wm[3] = wbf + 4*16384;                Dm[3] = Ki;   // wk_i
  Wm[4] = wbf + 5*16384;                Dm[4] = Vi;   // wv_i

  #pragma unroll
  for (int m = 0; m < 5; m++){
    f32x4 acc[8];
    #pragma unroll
    for (int c=0;c<8;c++) acc[c]=(f32x4){0,0,0,0};
    #pragma unroll
    for (int h = 0; h < 2; h++){
      __syncthreads();                               // prev readers done
      // stage half h: rows 64h..64h+63 of W (16KB), swizzled byte ^= (row&7)<<4
      const uint4* src = (const uint4*)(Wm[m] + h*8192);
      #pragma unroll
      for (int r = 0; r < 4; r++){
        int u = r*256 + tid;                         // 16B unit 0..1023
        uint32 sw = ((uint32)u*16) ^ (((uint32)(u>>4)&7u)<<4);
        *(uint4*)((char*)wlds + sw) = src[u];
      }
      __syncthreads();                               // staging visible
      #pragma unroll
      for (int kc = 0; kc < 4; kc++){
        #pragma unroll
        for (int ct = 0; ct < 4; ct++){
          uint32 rowh = (uint32)(ct*16 + lr);
          uint32 byte = (rowh*256u + (uint32)(kc*4 + jg)*16u) ^ ((rowh&7u)<<4);
          bf16x8 b = *(const bf16x8*)((const char*)wlds + byte);
          acc[h*4+ct] = __builtin_amdgcn_mfma_f32_16x16x32_bf16(aFrag[kc], b, acc[h*4+ct], 0, 0, 0);
        }
      }
    }
    tile_store_bf16(tlds[wvi], acc, Dm[m], row0, jg, lr, l);
  }
}

// ---------------- out-projection (wave-uniform weight select) + coalesced epilogue -------
__global__ __launch_bounds__(256,4) void out_all(const ushort_t* __restrict__ A,
    const ushort_t* __restrict__ wo_u, const ushort_t* __restrict__ wo_i,
    const float* __restrict__ bu, const float* __restrict__ bi_,
    const ushort_t* __restrict__ resid_bf, ushort_t* __restrict__ e_bf,
    float* __restrict__ total, float* __restrict__ total2){
  __shared__ float lds[4][16*132];
  int tid = threadIdx.x;
  int wvi = tid >> 6, l = tid & 63, lr = l & 15, jg = l >> 4;
  int row0 = blockIdx.x*64 + wvi*16;
  bool isU = row0 < USER_N;
  const bf16x8* Av = (const bf16x8*)A;
  const bf16x8* Bw = (const bf16x8*)(isU ? wo_u : wo_i);
  const float*  bias = isU ? bu : bi_;
  f32x4 acc[8];
  #pragma unroll
  for (int c=0;c<8;c++) acc[c]=(f32x4){0,0,0,0};
  #pragma unroll
  for (int kc = 0; kc < 4; kc++){
    int ko = kc*4 + jg;
    bf16x8 a = Av[(size_t)(row0 + lr)*16 + ko];
    #pragma unroll
    for (int ct=0;ct<8;ct++)
      acc[ct] = __builtin_amdgcn_mfma_f32_16x16x32_bf16(a, Bw[(size_t)(ct*16+lr)*16 + ko], acc[ct], 0, 0, 0);
  }
  float* T = lds[wvi];
  #pragma unroll
  for (int r=0;r<4;r++){
    int row = jg*4 + r;
    #pragma unroll
    for (int ct=0;ct<8;ct++) T[row*132 + ct*16 + lr] = acc[ct][r];
  }
  #pragma unroll
  for (int i=0;i<4;i++){
    int row = l & 15;
    int p = (l >> 4) + 4*i;
    int grow = row0 + row;
    size_t o = (size_t)grow*128 + p*8;
    const float* src = &T[row*132 + p*8];
    float4 a = *(const float4*)src;
    float4 b = *(const float4*)(src + 4);
    float4 ba = *(const float4*)&bias[p*8];
    float4 bb = *(const float4*)&bias[p*8 + 4];
    uint4 rr = *(const uint4*)&resid_bf[o];
    a.x += ba.x + bflo(rr.x); a.y += ba.y + bfhi(rr.x);
    a.z += ba.z + bflo(rr.y); a.w += ba.w + bfhi(rr.y);
    b.x += bb.x + bflo(rr.z); b.y += bb.y + bfhi(rr.z);
    b.z += bb.z + bflo(rr.w); b.w += bb.w + bfhi(rr.w);
    *(uint4*)&e_bf[o] = make_uint4(pack2(a.x,a.y), pack2(a.z,a.w), pack2(b.x,b.y), pack2(b.z,b.w));
    float4 t0 = *(const float4*)&total[o];
    float4 t1 = *(const float4*)&total[o + 4];
    t0.x += a.x; t0.y += a.y; t0.z += a.z; t0.w += a.w;
    t1.x += b.x; t1.y += b.y; t1.z += b.z; t1.w += b.w;
    *(float4*)&total[o]     = t0;
    *(float4*)&total[o + 4] = t1;
    if (total2){
      *(float4*)&total2[o]     = t0;
      *(float4*)&total2[o + 4] = t1;
    }
  }
}

// ------ attention: 2 waves per node (wave0: j=0..8, wave1: j=9..16), LDS softmax merge.
// Fused user+item dispatch. Doubles wave parallelism, halves per-wave chain length ->
// better latency hiding at identical gather traffic. ------------------------------------
__global__ __launch_bounds__(256) void attn_kernel(const ushort_t* __restrict__ QP,
    const ushort_t* __restrict__ Ku, const ushort_t* __restrict__ Vu,
    const ushort_t* __restrict__ Ki, const ushort_t* __restrict__ Vi,
    const int* __restrict__ samples, const float* __restrict__ pt,
    ushort_t* __restrict__ O){
  __shared__ float4 red[2][2][64];
  int tid = threadIdx.x;
  int wv = tid >> 6, lane = tid & 63;
  int pair = wv >> 1, half = wv & 1;
  int n = blockIdx.x*2 + pair;                 // block-uniform half (USER_N even)
  bool isU = n < USER_N;
  const uint32* K2 = (const uint32*)(isU ? Ku : Ki);
  const uint32* V2 = (const uint32*)(isU ? Vu : Vi);
  const float2* pK2 = (const float2*)(pt + (isU ? 0 : 2*17*128));
  const float2* pV2 = (const float2*)(pt + (isU ? 17*128 : 3*17*128));
  const float2* pQ2 = (const float2*)(pt + 4*17*128 + (isU ? 0 : 128));
  int smp = (lane < KK) ? samples[(size_t)n*KK + lane] : 0;
  const int j0  = half ? 9 : 0;
  const int cnt = half ? 8 : 9;
  // issue this wave's gathers up front
  uint32 ku[9], vu[9];
  #pragma unroll
  for (int t = 0; t < 9; t++){
    if (t < cnt){
      int j = j0 + t;
      int row = (j == 0) ? n : __shfl(smp, j-1, 64);
      ku[t] = K2[(size_t)row*64 + lane];
      vu[t] = V2[(size_t)row*64 + lane];
    }
  }
  float2 pq = pQ2[lane];
  uint32 qu = ((const uint32*)QP)[(size_t)n*64 + lane];
  float qx = bflo(qu) + pq.x, qy = bfhi(qu) + pq.y;
  float sc[9];
  #pragma unroll
  for (int t = 0; t < 9; t++){
    if (t < cnt){
      int j = j0 + t;
      float2 pk = pK2[j*64 + lane];
      float kx = bflo(ku[t]) + pk.x, ky = bfhi(ku[t]) + pk.y;
      float p = qx*kx + qy*ky;          // head = lane>>4 (dims 2*lane, 2*lane+1)
      p += __shfl_xor(p, 1, 64);
      p += __shfl_xor(p, 2, 64);
      p += __shfl_xor(p, 4, 64);
      p += __shfl_xor(p, 8, 64);
      sc[t] = p * 0.17677669529663687f; // 1/sqrt(32)
    } else sc[t] = -1e30f;
  }
  float m = sc[0];
  #pragma unroll
  for (int t = 1; t < 9; t++) m = fmaxf(m, sc[t]);
  float ss = 0.f, ox = 0.f, oy = 0.f;
  #pragma unroll
  for (int t = 0; t < 9; t++){
    if (t < cnt){
      float w = __expf(sc[t] - m);
      ss += w;
      int j = j0 + t;
      float2 pv = pV2[j*64 + lane];
      ox += w*(bflo(vu[t]) + pv.x);
      oy += w*(bfhi(vu[t]) + pv.y);
    }
  }
  red[pair][half][lane] = make_float4(m, ss, ox, oy);
  __syncthreads();
  if (half == 0){
    float4 a = red[pair][0][lane];
    float4 b = red[pair][1][lane];
    float mm = fmaxf(a.x, b.x);
    float ea = __expf(a.x - mm), eb = __expf(b.x - mm);
    float inv = 1.f / (a.y*ea + b.y*eb);
    float fx = (a.z*ea + b.z*eb)*inv;
    float fy = (a.w*ea + b.w*eb)*inv;
    ((uint32*)O)[(size_t)n*64 + lane] = pack2(fx, fy);
  }
}

extern "C" void kernel_launch(void* const* d_in, const int* in_sizes, int n_in,
                              void* d_out, int out_size, void* d_ws, size_t ws_size,
                              hipStream_t stream){
  const int*   adj_rows = (const int*)d_in[0];
  const int*   adj_cols = (const int*)d_in[1];
  const float* adj_vals = (const float*)d_in[2];
  const int*   samples  = (const int*)d_in[3];
  const float* user_emb = (const float*)d_in[4];
  const float* item_emb = (const float*)d_in[5];
  const float* pos_emb  = (const float*)d_in[6];
  const float* u_in_w   = (const float*)d_in[7];
  const float* u_in_b   = (const float*)d_in[8];
  const float* u_out_w  = (const float*)d_in[9];
  const float* u_out_b  = (const float*)d_in[10];
  const float* i_in_w   = (const float*)d_in[11];
  const float* i_in_b   = (const float*)d_in[12];
  const float* i_out_w  = (const float*)d_in[13];
  const float* i_out_b  = (const float*)d_in[14];
  float* out = (float*)d_out;

  char* ws = (char*)d_ws;
  size_t off = 0;
  auto alloc = [&](size_t bytes)->char*{
    char* p = ws + off; off += (bytes + 255) & ~(size_t)255; return p;
  };
  ushort_t* tmp_bf  = (ushort_t*)alloc((size_t)NN*DD*2);
  ushort_t* e_bf    = (ushort_t*)alloc((size_t)NN*DD*2);
  ushort_t* Qb      = (ushort_t*)alloc((size_t)NN*DD*2);
  ushort_t* Ku      = (ushort_t*)alloc((size_t)NN*DD*2);
  ushort_t* Vu      = (ushort_t*)alloc((size_t)NN*DD*2);
  ushort_t* Ki      = (ushort_t*)alloc((size_t)NN*DD*2);
  ushort_t* Vi      = (ushort_t*)alloc((size_t)NN*DD*2);
  ushort_t* Ob      = (ushort_t*)alloc((size_t)NN*DD*2);
  uint2*    csr     = (uint2*)   alloc((size_t)EE*8);
  int*      cntG    = (int*)     alloc((size_t)(NB*NG)*4);
  int*      baseG   = (int*)     alloc((size_t)(NB*NG)*4);
  int*      row_ptr = (int*)     alloc((size_t)(NN+1)*4);
  int*      bsum    = (int*)     alloc(320*4);
  int*      bpre    = (int*)     alloc(320*4);
  float*    pt      = (float*)   alloc((size_t)8960*4);
  ushort_t* wbf     = (ushort_t*)alloc((size_t)131072*2);

  // kv (12.8MB) aliases Ob: Ob first written by attn, long after s4 consumed kv.
  uint2* kv = (uint2*)Ob;

  ushort_t* wo_u = wbf + 6*16384;
  ushort_t* wo_i = wbf + 7*16384;

  init_e_total<<<NN*DD/4/256, 256, 0, stream>>>(user_emb, item_emb, e_bf, out);
  // ---- CSR build: single-level row counting sort ----
  s1_hist<<<NG, 256, 0, stream>>>(adj_rows, cntG);
  sum313<<<NB, 256, 0, stream>>>(cntG, bsum);
  scanb<<<1, 512, 0, stream>>>(bsum, bpre);
  scanE<<<NB, 256, 0, stream>>>(cntG, bpre, baseG);
  s3_scatter<<<NG, 256, 0, stream>>>(adj_rows, adj_cols, adj_vals, baseG, kv);
  s4_sort<<<NB, 256, 0, stream>>>(baseG, kv, row_ptr, csr);
  pos_proj<<<dim3(17,6), 128, 0, stream>>>(pos_emb, u_in_w, u_in_b, i_in_w, i_in_b, pt);
  cvt_weights<<<512, 256, 0, stream>>>(u_in_w, i_in_w, u_out_w, i_out_w, wbf);

  for (int it = 0; it < 2; it++){
    float* tot2 = (it == 1) ? (out + (size_t)NN*DD) : nullptr;
    spmm_kernel<<<NN/4, 256, 0, stream>>>(row_ptr, csr, e_bf, tmp_bf);
    gemm5<<<NN/64, 256, 0, stream>>>(tmp_bf, wbf, Qb, Ku, Vu, Ki, Vi);
    attn_kernel<<<NN/2, 256, 0, stream>>>(Qb, Ku, Vu, Ki, Vi, samples, pt, Ob);
    out_all<<<NN/64, 256, 0, stream>>>(Ob, wo_u, wo_i, u_out_b, i_out_b,
                                       tmp_bf, e_bf, out, tot2);
  }
}

// Round 6
// 723.834 us; speedup vs baseline: 1.4580x; 1.0115x over previous
//
#include <hip/hip_runtime.h>
#include <hip/hip_bf16.h>
#include <cstdint>
#include <cstddef>

#define USER_N 40000
#define ITEM_N 40000
#define NN     80000
#define DD     128
#define KK     16
#define EE     1600000

// counting-sort geometry: 313 buckets of 256 rows (313*256 = 80128), 256 edge-groups
#define NB    313
#define NG    256
#define EPG   (EE/NG)     // 6250
#define SCAP  5888        // LDS staging capacity per bucket (mean 5111, sigma ~71)

typedef __attribute__((ext_vector_type(8))) short bf16x8;
typedef __attribute__((ext_vector_type(4))) float f32x4;
typedef unsigned short ushort_t;
typedef unsigned int   uint32;

static __device__ __forceinline__ ushort_t f2bf(float x){
  __hip_bfloat16 h = __float2bfloat16(x);
  return *reinterpret_cast<ushort_t*>(&h);
}
static __device__ __forceinline__ float bflo(uint32 u){ return __uint_as_float(u << 16); }
static __device__ __forceinline__ float bfhi(uint32 u){ return __uint_as_float(u & 0xffff0000u); }
static __device__ __forceinline__ uint32 pack2(float a, float b){
  return (uint32)f2bf(a) | ((uint32)f2bf(b) << 16);
}

// ---------------- init: e_bf = bf16(concat(user,item)); total(d_out) = concat ----------------
__global__ void init_e_total(const float* __restrict__ user_emb, const float* __restrict__ item_emb,
                             ushort_t* __restrict__ e_bf, float* __restrict__ total){
  int idx = blockIdx.x*blockDim.x + threadIdx.x;           // float4 index
  const int n4 = NN*DD/4;
  if (idx >= n4) return;
  const int u4 = USER_N*DD/4;
  float4 v = (idx < u4) ? ((const float4*)user_emb)[idx] : ((const float4*)item_emb)[idx - u4];
  ((float4*)total)[idx] = v;
  ushort4 b; b.x = f2bf(v.x); b.y = f2bf(v.y); b.z = f2bf(v.z); b.w = f2bf(v.w);
  ((ushort4*)e_bf)[idx] = b;
}

// ---------------- weights -> bf16 ----------------
__global__ void cvt_weights(const float* __restrict__ u_in_w, const float* __restrict__ i_in_w,
                            const float* __restrict__ u_out_w, const float* __restrict__ i_out_w,
                            ushort_t* __restrict__ wbf){
  int i = blockIdx.x*256 + threadIdx.x;   // 512 blocks x 256 = 131072
  float v;
  if      (i < 49152)  v = u_in_w[i];
  else if (i < 98304)  v = i_in_w[i - 49152];
  else if (i < 114688) v = u_out_w[i - 98304];
  else                 v = i_out_w[i - 114688];
  wbf[i] = f2bf(v);
}

// ---------- CSR build: single-level row counting sort ----------
__global__ __launch_bounds__(256) void s1_hist(const int* __restrict__ rows,
                                               int* __restrict__ cntG){
  __shared__ int h[NB];
  int g = blockIdx.x, tid = threadIdx.x;
  for (int b = tid; b < NB; b += 256) h[b] = 0;
  __syncthreads();
  int s = g*EPG;
  for (int i = s + tid; i < s + EPG; i += 256)
    atomicAdd(&h[rows[i] >> 8], 1);
  __syncthreads();
  for (int b = tid; b < NB; b += 256) cntG[b*NG + g] = h[b];
}

// S2a: per-256-chunk sums (313 blocks exactly cover 80128 entries)
__global__ void sum313(const int* __restrict__ in, int* __restrict__ bsum){
  __shared__ int s[256];
  s[threadIdx.x] = in[blockIdx.x*256 + threadIdx.x];
  __syncthreads();
  for (int o = 128; o > 0; o >>= 1){
    if (threadIdx.x < o) s[threadIdx.x] += s[threadIdx.x + o];
    __syncthreads();
  }
  if (threadIdx.x == 0) bsum[blockIdx.x] = s[0];
}

// S2b: exclusive scan of the 313 chunk sums
__global__ void scanb(const int* __restrict__ bsum, int* __restrict__ bpre){
  __shared__ int s[512];
  int v = (threadIdx.x < NB) ? bsum[threadIdx.x] : 0;
  s[threadIdx.x] = v;
  __syncthreads();
  for (int o = 1; o < 512; o <<= 1){
    int t = (threadIdx.x >= o) ? s[threadIdx.x - o] : 0;
    __syncthreads();
    s[threadIdx.x] += t;
    __syncthreads();
  }
  if (threadIdx.x < NB) bpre[threadIdx.x] = s[threadIdx.x] - v;
}

// S2c: per-element exclusive prefix
__global__ void scanE(const int* __restrict__ in, const int* __restrict__ bpre,
                      int* __restrict__ baseX){
  __shared__ int s[256];
  int i = blockIdx.x*256 + threadIdx.x;
  int v = in[i];
  s[threadIdx.x] = v;
  __syncthreads();
  for (int o = 1; o < 256; o <<= 1){
    int t = (threadIdx.x >= o) ? s[threadIdx.x - o] : 0;
    __syncthreads();
    s[threadIdx.x] += t;
    __syncthreads();
  }
  baseX[i] = bpre[blockIdx.x] + s[threadIdx.x] - v;
}

// S3: scatter edges into row-bucket-major order; block-private sequential regions.
// kv entry: x = (row&255)<<17 | col, y = val bits.
__global__ __launch_bounds__(256) void s3_scatter(const int* __restrict__ rows,
    const int* __restrict__ cols, const float* __restrict__ vals,
    const int* __restrict__ baseG, uint2* __restrict__ kv){
  __shared__ int cur[NB];
  int g = blockIdx.x, tid = threadIdx.x;
  for (int b = tid; b < NB; b += 256) cur[b] = baseG[b*NG + g];
  __syncthreads();
  int s = g*EPG;
  for (int i = s + tid; i < s + EPG; i += 256){
    int r = rows[i];
    int p = atomicAdd(&cur[r >> 8], 1);
    kv[p] = make_uint2(((uint32)(r & 255) << 17) | (uint32)cols[i], __float_as_uint(vals[i]));
  }
}

// S4: one block per row-bucket. Stage in LDS, histogram 256 rows, scan, emit row_ptr,
// scatter to final CSR slots (contiguous ~41KB per block).
__global__ __launch_bounds__(256) void s4_sort(const int* __restrict__ baseG,
    const uint2* __restrict__ kv, int* __restrict__ row_ptr, uint2* __restrict__ csr){
  __shared__ uint2 stage[SCAP];
  __shared__ int hist[256], sc[256], curs[256];
  int b = blockIdx.x, tid = threadIdx.x;
  int start = baseG[b*NG];
  int end   = (b == NB-1) ? EE : baseG[(b+1)*NG];
  int cnt = end - start;
  hist[tid] = 0;
  __syncthreads();
  for (int i = tid; i < cnt; i += 256){
    uint2 e = kv[start + i];
    if (i < SCAP) stage[i] = e;
    atomicAdd(&hist[e.x >> 17], 1);
  }
  __syncthreads();
  int v = hist[tid];
  sc[tid] = v;
  __syncthreads();
  for (int o = 1; o < 256; o <<= 1){
    int t = (tid >= o) ? sc[tid - o] : 0;
    __syncthreads();
    sc[tid] += t;
    __syncthreads();
  }
  int ex = sc[tid] - v;          // exclusive prefix within bucket
  curs[tid] = ex;
  int grow = b*256 + tid;
  if (grow <= NN) row_ptr[grow] = start + ex;   // covers row_ptr[NN] (b=312, tid=128)
  __syncthreads();
  for (int i = tid; i < cnt; i += 256){
    uint2 e = (i < SCAP) ? stage[i] : kv[start + i];
    int r = (int)(e.x >> 17);
    int p = atomicAdd(&curs[r], 1);
    csr[start + p] = make_uint2(e.x & 0x1FFFFu, e.y);
  }
}

// ---------------- SpMM: one wave per row; 16-deep pipelined gathers ---------------------
// r4 showed the gather plateau is MLP-limited (2.0 vs attn's 2.6 TB/s at higher occupancy)
// -> double the in-flight gather front per wave.
__global__ __launch_bounds__(256) void spmm_kernel(const int* __restrict__ row_ptr,
    const uint2* __restrict__ csr, const ushort_t* __restrict__ e_bf,
    ushort_t* __restrict__ tmp_bf){
  int wid  = (blockIdx.x*blockDim.x + threadIdx.x) >> 6;
  int lane = threadIdx.x & 63;
  if (wid >= NN) return;
  int s = row_ptr[wid], t = row_ptr[wid+1];
  const uint32* E = (const uint32*)e_bf;   // 2 bf16 per uint
  float ax = 0.f, ay = 0.f;
  int e = s;
  for (; e + 16 <= t; e += 16){
    uint2 c[16];
    #pragma unroll
    for (int k=0;k<16;k++) c[k] = csr[e+k];
    uint32 x[16];
    #pragma unroll
    for (int k=0;k<16;k++) x[k] = E[(size_t)c[k].x*64 + lane];
    #pragma unroll
    for (int k=0;k<16;k++){
      float v = __uint_as_float(c[k].y);
      ax += v*bflo(x[k]); ay += v*bfhi(x[k]);
    }
  }
  for (; e + 8 <= t; e += 8){
    uint2 c[8];
    #pragma unroll
    for (int k=0;k<8;k++) c[k] = csr[e+k];
    uint32 x[8];
    #pragma unroll
    for (int k=0;k<8;k++) x[k] = E[(size_t)c[k].x*64 + lane];
    #pragma unroll
    for (int k=0;k<8;k++){
      float v = __uint_as_float(c[k].y);
      ax += v*bflo(x[k]); ay += v*bfhi(x[k]);
    }
  }
  for (; e + 4 <= t; e += 4){
    uint2 c[4];
    #pragma unroll
    for (int k=0;k<4;k++) c[k] = csr[e+k];
    uint32 x[4];
    #pragma unroll
    for (int k=0;k<4;k++) x[k] = E[(size_t)c[k].x*64 + lane];
    #pragma unroll
    for (int k=0;k<4;k++){
      float v = __uint_as_float(c[k].y);
      ax += v*bflo(x[k]); ay += v*bfhi(x[k]);
    }
  }
  for (; e < t; e++){
    uint2 c0 = csr[e];
    float v0 = __uint_as_float(c0.y);
    uint32 x0 = E[(size_t)c0.x*64 + lane];
    ax += v0*bflo(x0); ay += v0*bfhi(x0);
  }
  ((uint32*)tmp_bf)[(size_t)wid*64 + lane] = pack2(ax, ay);
}

// ---------------- pos tables (fp32): pos_emb @ W.T + b for Q/K/V, u/i ----------------
__global__ void pos_proj(const float* __restrict__ pos_emb,
                         const float* __restrict__ u_in_w, const float* __restrict__ u_in_b,
                         const float* __restrict__ i_in_w, const float* __restrict__ i_in_b,
                         float* __restrict__ pt){
  int j = blockIdx.x;      // 0..16
  int m = blockIdx.y;      // 0..5
  int d = threadIdx.x;     // 0..127
  if (m >= 4 && j > 0) return;
  const float* w; const float* b; float* out; int roff;
  switch (m){
    case 0: w=u_in_w; b=u_in_b; roff=128; out=pt + j*128;            break; // posK_u
    case 1: w=u_in_w; b=u_in_b; roff=256; out=pt + 17*128 + j*128;   break; // posV_u
    case 2: w=i_in_w; b=i_in_b; roff=128; out=pt + 2*17*128 + j*128; break; // posK_i
    case 3: w=i_in_w; b=i_in_b; roff=256; out=pt + 3*17*128 + j*128; break; // posV_i
    case 4: w=u_in_w; b=u_in_b; roff=0;   out=pt + 4*17*128;         break; // posQ_u
    default:w=i_in_w; b=i_in_b; roff=0;   out=pt + 4*17*128 + 128;   break; // posQ_i
  }
  int row = roff + d;
  float acc = b[row];
  for (int c = 0; c < DD; c++) acc += pos_emb[j*DD + c] * w[row*DD + c];
  out[d] = acc;
}

// ---- wave-private LDS transpose of a 16x128 MFMA C-tile, then coalesced bf16 stores ----
// stride parameterized so K and V can interleave per row (KV table, stride 256).
static __device__ __forceinline__ void tile_store_bf16(float* __restrict__ T,
    const f32x4* acc, ushort_t* __restrict__ dst, int row0, int jg, int lr, int l,
    int stride){
  #pragma unroll
  for (int r=0;r<4;r++){
    int row = jg*4 + r;
    #pragma unroll
    for (int ct=0;ct<8;ct++) T[row*132 + ct*16 + lr] = acc[ct][r];
  }
  // wave-private: no barrier needed, compiler orders ds via lgkmcnt
  #pragma unroll
  for (int i=0;i<4;i++){
    int row = l & 15;
    int p = (l >> 4) + 4*i;          // 16B-pair index 0..15 (8 cols each)
    const float* src = &T[row*132 + p*8];
    float4 a = *(const float4*)src;
    float4 b = *(const float4*)(src + 4);
    uint4 w = make_uint4(pack2(a.x,a.y), pack2(a.z,a.w), pack2(b.x,b.y), pack2(b.z,b.w));
    *(uint4*)&dst[(size_t)(row0 + row)*stride + p*8] = w;
  }
}

// ------- 5-in-1 GEMM: A-frags register-resident, reused across 5 weight matrices;
// weights staged global->LDS (XOR-swizzled). K/V outputs interleave into KV tables. ------
__global__ __launch_bounds__(256,3) void gemm5(const ushort_t* __restrict__ A,
    const ushort_t* __restrict__ wbf, ushort_t* __restrict__ Qb,
    ushort_t* __restrict__ KVu, ushort_t* __restrict__ KVi){
  __shared__ ushort_t wlds[8192];          // 16KB: one half-matrix (64 rows x 128 k)
  __shared__ float   tlds[4][16*132];      // 33.8KB transpose buffers (wave-private)
  int tid = threadIdx.x;
  int wvi = tid >> 6, l = tid & 63, lr = l & 15, jg = l >> 4;
  int row0 = blockIdx.x*64 + wvi*16;
  bool isU = (blockIdx.x*64) < USER_N;     // block-uniform (64 | 40000)

  // A fragments: 16 rows x 128 k in registers, reused for all 5 matrices
  const bf16x8* Av = (const bf16x8*)A;
  bf16x8 aFrag[4];
  #pragma unroll
  for (int kc = 0; kc < 4; kc++)
    aFrag[kc] = Av[(size_t)(row0 + lr)*16 + kc*4 + jg];

  const ushort_t* Wm[5];
  ushort_t* Dm[5];
  int St[5];
  Wm[0] = isU ? wbf : (wbf + 3*16384);  Dm[0] = Qb;        St[0] = 128; // wq
  Wm[1] = wbf + 16384;                  Dm[1] = KVu;       St[1] = 256; // wk_u -> K half
  Wm[2] = wbf + 2*16384;                Dm[2] = KVu + 128; St[2] = 256; // wv_u -> V half
  Wm[3] = wbf + 4*16384;                Dm[3] = KVi;       St[3] = 256; // wk_i
  Wm[4] = wbf + 5*16384;                Dm[4] = KVi + 128; St[4] = 256; // wv_i

  #pragma unroll
  for (int m = 0; m < 5; m++){
    f32x4 acc[8];
    #pragma unroll
    for (int c=0;c<8;c++) acc[c]=(f32x4){0,0,0,0};
    #pragma unroll
    for (int h = 0; h < 2; h++){
      __syncthreads();                               // prev readers done
      // stage half h: rows 64h..64h+63 of W (16KB), swizzled byte ^= (row&7)<<4
      const uint4* src = (const uint4*)(Wm[m] + h*8192);
      #pragma unroll
      for (int r = 0; r < 4; r++){
        int u = r*256 + tid;                         // 16B unit 0..1023
        uint32 sw = ((uint32)u*16) ^ (((uint32)(u>>4)&7u)<<4);
        *(uint4*)((char*)wlds + sw) = src[u];
      }
      __syncthreads();                               // staging visible
      #pragma unroll
      for (int kc = 0; kc < 4; kc++){
        #pragma unroll
        for (int ct = 0; ct < 4; ct++){
          uint32 rowh = (uint32)(ct*16 + lr);
          uint32 byte = (rowh*256u + (uint32)(kc*4 + jg)*16u) ^ ((rowh&7u)<<4);
          bf16x8 b = *(const bf16x8*)((const char*)wlds + byte);
          acc[h*4+ct] = __builtin_amdgcn_mfma_f32_16x16x32_bf16(aFrag[kc], b, acc[h*4+ct], 0, 0, 0);
        }
      }
    }
    tile_store_bf16(tlds[wvi], acc, Dm[m], row0, jg, lr, l, St[m]);
  }
}

// ---------------- out-projection (wave-uniform weight select) + coalesced epilogue -------
__global__ __launch_bounds__(256,4) void out_all(const ushort_t* __restrict__ A,
    const ushort_t* __restrict__ wo_u, const ushort_t* __restrict__ wo_i,
    const float* __restrict__ bu, const float* __restrict__ bi_,
    const ushort_t* __restrict__ resid_bf, ushort_t* __restrict__ e_bf,
    float* __restrict__ total, float* __restrict__ total2){
  __shared__ float lds[4][16*132];
  int tid = threadIdx.x;
  int wvi = tid >> 6, l = tid & 63, lr = l & 15, jg = l >> 4;
  int row0 = blockIdx.x*64 + wvi*16;
  bool isU = row0 < USER_N;
  const bf16x8* Av = (const bf16x8*)A;
  const bf16x8* Bw = (const bf16x8*)(isU ? wo_u : wo_i);
  const float*  bias = isU ? bu : bi_;
  f32x4 acc[8];
  #pragma unroll
  for (int c=0;c<8;c++) acc[c]=(f32x4){0,0,0,0};
  #pragma unroll
  for (int kc = 0; kc < 4; kc++){
    int ko = kc*4 + jg;
    bf16x8 a = Av[(size_t)(row0 + lr)*16 + ko];
    #pragma unroll
    for (int ct=0;ct<8;ct++)
      acc[ct] = __builtin_amdgcn_mfma_f32_16x16x32_bf16(a, Bw[(size_t)(ct*16+lr)*16 + ko], acc[ct], 0, 0, 0);
  }
  float* T = lds[wvi];
  #pragma unroll
  for (int r=0;r<4;r++){
    int row = jg*4 + r;
    #pragma unroll
    for (int ct=0;ct<8;ct++) T[row*132 + ct*16 + lr] = acc[ct][r];
  }
  #pragma unroll
  for (int i=0;i<4;i++){
    int row = l & 15;
    int p = (l >> 4) + 4*i;
    int grow = row0 + row;
    size_t o = (size_t)grow*128 + p*8;
    const float* src = &T[row*132 + p*8];
    float4 a = *(const float4*)src;
    float4 b = *(const float4*)(src + 4);
    float4 ba = *(const float4*)&bias[p*8];
    float4 bb = *(const float4*)&bias[p*8 + 4];
    uint4 rr = *(const uint4*)&resid_bf[o];
    a.x += ba.x + bflo(rr.x); a.y += ba.y + bfhi(rr.x);
    a.z += ba.z + bflo(rr.y); a.w += ba.w + bfhi(rr.y);
    b.x += bb.x + bflo(rr.z); b.y += bb.y + bfhi(rr.z);
    b.z += bb.z + bflo(rr.w); b.w += bb.w + bfhi(rr.w);
    *(uint4*)&e_bf[o] = make_uint4(pack2(a.x,a.y), pack2(a.z,a.w), pack2(b.x,b.y), pack2(b.z,b.w));
    float4 t0 = *(const float4*)&total[o];
    float4 t1 = *(const float4*)&total[o + 4];
    t0.x += a.x; t0.y += a.y; t0.z += a.z; t0.w += a.w;
    t1.x += b.x; t1.y += b.y; t1.z += b.z; t1.w += b.w;
    *(float4*)&total[o]     = t0;
    *(float4*)&total[o + 4] = t1;
    if (total2){
      *(float4*)&total2[o]     = t0;
      *(float4*)&total2[o + 4] = t1;
    }
  }
}

// ------ attention: 2 waves per node (wave0: j=0..8, wave1: j=9..16), LDS softmax merge.
// KV interleaved table: one address per j serves both K (base) and V (base+64 words). ----
__global__ __launch_bounds__(256) void attn_kernel(const ushort_t* __restrict__ QP,
    const ushort_t* __restrict__ KVu, const ushort_t* __restrict__ KVi,
    const int* __restrict__ samples, const float* __restrict__ pt,
    ushort_t* __restrict__ O){
  __shared__ float4 red[2][2][64];
  int tid = threadIdx.x;
  int wv = tid >> 6, lane = tid & 63;
  int pair = wv >> 1, half = wv & 1;
  int n = blockIdx.x*2 + pair;                 // block-uniform half (USER_N even)
  bool isU = n < USER_N;
  const uint32* KV2 = (const uint32*)(isU ? KVu : KVi);
  const float2* pK2 = (const float2*)(pt + (isU ? 0 : 2*17*128));
  const float2* pV2 = (const float2*)(pt + (isU ? 17*128 : 3*17*128));
  const float2* pQ2 = (const float2*)(pt + 4*17*128 + (isU ? 0 : 128));
  int smp = (lane < KK) ? samples[(size_t)n*KK + lane] : 0;
  const int j0  = half ? 9 : 0;
  const int cnt = half ? 8 : 9;
  // issue this wave's gathers up front (shared base per j: K at +0, V at +64 words)
  uint32 ku[9], vu[9];
  #pragma unroll
  for (int t = 0; t < 9; t++){
    if (t < cnt){
      int j = j0 + t;
      int row = (j == 0) ? n : __shfl(smp, j-1, 64);
      size_t o = (size_t)row*128 + lane;
      ku[t] = KV2[o];
      vu[t] = KV2[o + 64];
    }
  }
  float2 pq = pQ2[lane];
  uint32 qu = ((const uint32*)QP)[(size_t)n*64 + lane];
  float qx = bflo(qu) + pq.x, qy = bfhi(qu) + pq.y;
  float sc[9];
  #pragma unroll
  for (int t = 0; t < 9; t++){
    if (t < cnt){
      int j = j0 + t;
      float2 pk = pK2[j*64 + lane];
      float kx = bflo(ku[t]) + pk.x, ky = bfhi(ku[t]) + pk.y;
      float p = qx*kx + qy*ky;          // head = lane>>4 (dims 2*lane, 2*lane+1)
      p += __shfl_xor(p, 1, 64);
      p += __shfl_xor(p, 2, 64);
      p += __shfl_xor(p, 4, 64);
      p += __shfl_xor(p, 8, 64);
      sc[t] = p * 0.17677669529663687f; // 1/sqrt(32)
    } else sc[t] = -1e30f;
  }
  float m = sc[0];
  #pragma unroll
  for (int t = 1; t < 9; t++) m = fmaxf(m, sc[t]);
  float ss = 0.f, ox = 0.f, oy = 0.f;
  #pragma unroll
  for (int t = 0; t < 9; t++){
    if (t < cnt){
      float w = __expf(sc[t] - m);
      ss += w;
      int j = j0 + t;
      float2 pv = pV2[j*64 + lane];
      ox += w*(bflo(vu[t]) + pv.x);
      oy += w*(bfhi(vu[t]) + pv.y);
    }
  }
  red[pair][half][lane] = make_float4(m, ss, ox, oy);
  __syncthreads();
  if (half == 0){
    float4 a = red[pair][0][lane];
    float4 b = red[pair][1][lane];
    float mm = fmaxf(a.x, b.x);
    float ea = __expf(a.x - mm), eb = __expf(b.x - mm);
    float inv = 1.f / (a.y*ea + b.y*eb);
    float fx = (a.z*ea + b.z*eb)*inv;
    float fy = (a.w*ea + b.w*eb)*inv;
    ((uint32*)O)[(size_t)n*64 + lane] = pack2(fx, fy);
  }
}

extern "C" void kernel_launch(void* const* d_in, const int* in_sizes, int n_in,
                              void* d_out, int out_size, void* d_ws, size_t ws_size,
                              hipStream_t stream){
  const int*   adj_rows = (const int*)d_in[0];
  const int*   adj_cols = (const int*)d_in[1];
  const float* adj_vals = (const float*)d_in[2];
  const int*   samples  = (const int*)d_in[3];
  const float* user_emb = (const float*)d_in[4];
  const float* item_emb = (const float*)d_in[5];
  const float* pos_emb  = (const float*)d_in[6];
  const float* u_in_w   = (const float*)d_in[7];
  const float* u_in_b   = (const float*)d_in[8];
  const float* u_out_w  = (const float*)d_in[9];
  const float* u_out_b  = (const float*)d_in[10];
  const float* i_in_w   = (const float*)d_in[11];
  const float* i_in_b   = (const float*)d_in[12];
  const float* i_out_w  = (const float*)d_in[13];
  const float* i_out_b  = (const float*)d_in[14];
  float* out = (float*)d_out;

  char* ws = (char*)d_ws;
  size_t off = 0;
  auto alloc = [&](size_t bytes)->char*{
    char* p = ws + off; off += (bytes + 255) & ~(size_t)255; return p;
  };
  ushort_t* tmp_bf  = (ushort_t*)alloc((size_t)NN*DD*2);
  ushort_t* e_bf    = (ushort_t*)alloc((size_t)NN*DD*2);
  ushort_t* Qb      = (ushort_t*)alloc((size_t)NN*DD*2);
  ushort_t* KVu     = (ushort_t*)alloc((size_t)NN*DD*4);   // K|V interleaved, 41MB
  ushort_t* KVi     = (ushort_t*)alloc((size_t)NN*DD*4);
  ushort_t* Ob      = (ushort_t*)alloc((size_t)NN*DD*2);
  uint2*    csr     = (uint2*)   alloc((size_t)EE*8);
  int*      cntG    = (int*)     alloc((size_t)(NB*NG)*4);
  int*      baseG   = (int*)     alloc((size_t)(NB*NG)*4);
  int*      row_ptr = (int*)     alloc((size_t)(NN+1)*4);
  int*      bsum    = (int*)     alloc(320*4);
  int*      bpre    = (int*)     alloc(320*4);
  float*    pt      = (float*)   alloc((size_t)8960*4);
  ushort_t* wbf     = (ushort_t*)alloc((size_t)131072*2);

  // kv (12.8MB) aliases Ob: Ob first written by attn, long after s4 consumed kv.
  uint2* kv = (uint2*)Ob;

  ushort_t* wo_u = wbf + 6*16384;
  ushort_t* wo_i = wbf + 7*16384;

  init_e_total<<<NN*DD/4/256, 256, 0, stream>>>(user_emb, item_emb, e_bf, out);
  // ---- CSR build: single-level row counting sort ----
  s1_hist<<<NG, 256, 0, stream>>>(adj_rows, cntG);
  sum313<<<NB, 256, 0, stream>>>(cntG, bsum);
  scanb<<<1, 512, 0, stream>>>(bsum, bpre);
  scanE<<<NB, 256, 0, stream>>>(cntG, bpre, baseG);
  s3_scatter<<<NG, 256, 0, stream>>>(adj_rows, adj_cols, adj_vals, baseG, kv);
  s4_sort<<<NB, 256, 0, stream>>>(baseG, kv, row_ptr, csr);
  pos_proj<<<dim3(17,6), 128, 0, stream>>>(pos_emb, u_in_w, u_in_b, i_in_w, i_in_b, pt);
  cvt_weights<<<512, 256, 0, stream>>>(u_in_w, i_in_w, u_out_w, i_out_w, wbf);

  for (int it = 0; it < 2; it++){
    float* tot2 = (it == 1) ? (out + (size_t)NN*DD) : nullptr;
    spmm_kernel<<<NN/4, 256, 0, stream>>>(row_ptr, csr, e_bf, tmp_bf);
    gemm5<<<NN/64, 256, 0, stream>>>(tmp_bf, wbf, Qb, KVu, KVi);
    attn_kernel<<<NN/2, 256, 0, stream>>>(Qb, KVu, KVi, samples, pt, Ob);
    out_all<<<NN/64, 256, 0, stream>>>(Ob, wo_u, wo_i, u_out_b, i_out_b,
                                       tmp_bf, e_bf, out, tot2);
  }
}

// Round 8
// 692.389 us; speedup vs baseline: 1.5243x; 1.0454x over previous
//
#include <hip/hip_runtime.h>
#include <hip/hip_bf16.h>
#include <cstdint>
#include <cstddef>

#define USER_N 40000
#define ITEM_N 40000
#define NN     80000
#define DD     128
#define KK     16
#define EE     1600000

// counting-sort geometry: 313 buckets of 256 rows (313*256 = 80128), 256 edge-groups
#define NB    313
#define NG    256
#define EPG   (EE/NG)     // 6250
#define SCAP  5888        // LDS staging capacity per bucket (mean 5111, sigma ~71)

typedef __attribute__((ext_vector_type(8))) short bf16x8;
typedef __attribute__((ext_vector_type(4))) float f32x4;
typedef unsigned short ushort_t;
typedef unsigned int   uint32;

static __device__ __forceinline__ ushort_t f2bf(float x){
  __hip_bfloat16 h = __float2bfloat16(x);
  return *reinterpret_cast<ushort_t*>(&h);
}
static __device__ __forceinline__ float bflo(uint32 u){ return __uint_as_float(u << 16); }
static __device__ __forceinline__ float bfhi(uint32 u){ return __uint_as_float(u & 0xffff0000u); }
static __device__ __forceinline__ uint32 pack2(float a, float b){
  return (uint32)f2bf(a) | ((uint32)f2bf(b) << 16);
}

// ---------------- init: e_bf = bf16(concat(user,item)); total(d_out) = concat ----------------
__global__ void init_e_total(const float* __restrict__ user_emb, const float* __restrict__ item_emb,
                             ushort_t* __restrict__ e_bf, float* __restrict__ total){
  int idx = blockIdx.x*blockDim.x + threadIdx.x;           // float4 index
  const int n4 = NN*DD/4;
  if (idx >= n4) return;
  const int u4 = USER_N*DD/4;
  float4 v = (idx < u4) ? ((const float4*)user_emb)[idx] : ((const float4*)item_emb)[idx - u4];
  ((float4*)total)[idx] = v;
  ushort4 b; b.x = f2bf(v.x); b.y = f2bf(v.y); b.z = f2bf(v.z); b.w = f2bf(v.w);
  ((ushort4*)e_bf)[idx] = b;
}

// ---------------- weights -> bf16 ----------------
__global__ void cvt_weights(const float* __restrict__ u_in_w, const float* __restrict__ i_in_w,
                            const float* __restrict__ u_out_w, const float* __restrict__ i_out_w,
                            ushort_t* __restrict__ wbf){
  int i = blockIdx.x*256 + threadIdx.x;   // 512 blocks x 256 = 131072
  float v;
  if      (i < 49152)  v = u_in_w[i];
  else if (i < 98304)  v = i_in_w[i - 49152];
  else if (i < 114688) v = u_out_w[i - 98304];
  else                 v = i_out_w[i - 114688];
  wbf[i] = f2bf(v);
}

// ---------- CSR build: single-level row counting sort ----------
__global__ __launch_bounds__(256) void s1_hist(const int* __restrict__ rows,
                                               int* __restrict__ cntG){
  __shared__ int h[NB];
  int g = blockIdx.x, tid = threadIdx.x;
  for (int b = tid; b < NB; b += 256) h[b] = 0;
  __syncthreads();
  int s = g*EPG;
  for (int i = s + tid; i < s + EPG; i += 256)
    atomicAdd(&h[rows[i] >> 8], 1);
  __syncthreads();
  for (int b = tid; b < NB; b += 256) cntG[b*NG + g] = h[b];
}

// S2a: per-256-chunk sums (313 blocks exactly cover 80128 entries)
__global__ void sum313(const int* __restrict__ in, int* __restrict__ bsum){
  __shared__ int s[256];
  s[threadIdx.x] = in[blockIdx.x*256 + threadIdx.x];
  __syncthreads();
  for (int o = 128; o > 0; o >>= 1){
    if (threadIdx.x < o) s[threadIdx.x] += s[threadIdx.x + o];
    __syncthreads();
  }
  if (threadIdx.x == 0) bsum[blockIdx.x] = s[0];
}

// S2b: exclusive scan of the 313 chunk sums
__global__ void scanb(const int* __restrict__ bsum, int* __restrict__ bpre){
  __shared__ int s[512];
  int v = (threadIdx.x < NB) ? bsum[threadIdx.x] : 0;
  s[threadIdx.x] = v;
  __syncthreads();
  for (int o = 1; o < 512; o <<= 1){
    int t = (threadIdx.x >= o) ? s[threadIdx.x - o] : 0;
    __syncthreads();
    s[threadIdx.x] += t;
    __syncthreads();
  }
  if (threadIdx.x < NB) bpre[threadIdx.x] = s[threadIdx.x] - v;
}

// S2c: per-element exclusive prefix
__global__ void scanE(const int* __restrict__ in, const int* __restrict__ bpre,
                      int* __restrict__ baseX){
  __shared__ int s[256];
  int i = blockIdx.x*256 + threadIdx.x;
  int v = in[i];
  s[threadIdx.x] = v;
  __syncthreads();
  for (int o = 1; o < 256; o <<= 1){
    int t = (threadIdx.x >= o) ? s[threadIdx.x - o] : 0;
    __syncthreads();
    s[threadIdx.x] += t;
    __syncthreads();
  }
  baseX[i] = bpre[blockIdx.x] + s[threadIdx.x] - v;
}

// S3: scatter edges into row-bucket-major order; block-private sequential regions.
// kv entry: x = (row&255)<<17 | col, y = val bits.
__global__ __launch_bounds__(256) void s3_scatter(const int* __restrict__ rows,
    const int* __restrict__ cols, const float* __restrict__ vals,
    const int* __restrict__ baseG, uint2* __restrict__ kv){
  __shared__ int cur[NB];
  int g = blockIdx.x, tid = threadIdx.x;
  for (int b = tid; b < NB; b += 256) cur[b] = baseG[b*NG + g];
  __syncthreads();
  int s = g*EPG;
  for (int i = s + tid; i < s + EPG; i += 256){
    int r = rows[i];
    int p = atomicAdd(&cur[r >> 8], 1);
    kv[p] = make_uint2(((uint32)(r & 255) << 17) | (uint32)cols[i], __float_as_uint(vals[i]));
  }
}

// S4: one block per row-bucket. Stage in LDS, histogram 256 rows, scan, emit row_ptr,
// scatter to final CSR slots (contiguous ~41KB per block).
__global__ __launch_bounds__(256) void s4_sort(const int* __restrict__ baseG,
    const uint2* __restrict__ kv, int* __restrict__ row_ptr, uint2* __restrict__ csr){
  __shared__ uint2 stage[SCAP];
  __shared__ int hist[256], sc[256], curs[256];
  int b = blockIdx.x, tid = threadIdx.x;
  int start = baseG[b*NG];
  int end   = (b == NB-1) ? EE : baseG[(b+1)*NG];
  int cnt = end - start;
  hist[tid] = 0;
  __syncthreads();
  for (int i = tid; i < cnt; i += 256){
    uint2 e = kv[start + i];
    if (i < SCAP) stage[i] = e;
    atomicAdd(&hist[e.x >> 17], 1);
  }
  __syncthreads();
  int v = hist[tid];
  sc[tid] = v;
  __syncthreads();
  for (int o = 1; o < 256; o <<= 1){
    int t = (tid >= o) ? sc[tid - o] : 0;
    __syncthreads();
    sc[tid] += t;
    __syncthreads();
  }
  int ex = sc[tid] - v;          // exclusive prefix within bucket
  curs[tid] = ex;
  int grow = b*256 + tid;
  if (grow <= NN) row_ptr[grow] = start + ex;   // covers row_ptr[NN] (b=312, tid=128)
  __syncthreads();
  for (int i = tid; i < cnt; i += 256){
    uint2 e = (i < SCAP) ? stage[i] : kv[start + i];
    int r = (int)(e.x >> 17);
    int p = atomicAdd(&curs[r], 1);
    csr[start + p] = make_uint2(e.x & 0x1FFFFu, e.y);
  }
}

// ---------------- SpMM: one wave per row; 16-deep pipelined gathers ---------------------
__global__ __launch_bounds__(256) void spmm_kernel(const int* __restrict__ row_ptr,
    const uint2* __restrict__ csr, const ushort_t* __restrict__ e_bf,
    ushort_t* __restrict__ tmp_bf){
  int wid  = (blockIdx.x*blockDim.x + threadIdx.x) >> 6;
  int lane = threadIdx.x & 63;
  if (wid >= NN) return;
  int s = row_ptr[wid], t = row_ptr[wid+1];
  const uint32* E = (const uint32*)e_bf;   // 2 bf16 per uint
  float ax = 0.f, ay = 0.f;
  int e = s;
  for (; e + 16 <= t; e += 16){
    uint2 c[16];
    #pragma unroll
    for (int k=0;k<16;k++) c[k] = csr[e+k];
    uint32 x[16];
    #pragma unroll
    for (int k=0;k<16;k++) x[k] = E[(size_t)c[k].x*64 + lane];
    #pragma unroll
    for (int k=0;k<16;k++){
      float v = __uint_as_float(c[k].y);
      ax += v*bflo(x[k]); ay += v*bfhi(x[k]);
    }
  }
  for (; e + 8 <= t; e += 8){
    uint2 c[8];
    #pragma unroll
    for (int k=0;k<8;k++) c[k] = csr[e+k];
    uint32 x[8];
    #pragma unroll
    for (int k=0;k<8;k++) x[k] = E[(size_t)c[k].x*64 + lane];
    #pragma unroll
    for (int k=0;k<8;k++){
      float v = __uint_as_float(c[k].y);
      ax += v*bflo(x[k]); ay += v*bfhi(x[k]);
    }
  }
  for (; e + 4 <= t; e += 4){
    uint2 c[4];
    #pragma unroll
    for (int k=0;k<4;k++) c[k] = csr[e+k];
    uint32 x[4];
    #pragma unroll
    for (int k=0;k<4;k++) x[k] = E[(size_t)c[k].x*64 + lane];
    #pragma unroll
    for (int k=0;k<4;k++){
      float v = __uint_as_float(c[k].y);
      ax += v*bflo(x[k]); ay += v*bfhi(x[k]);
    }
  }
  for (; e < t; e++){
    uint2 c0 = csr[e];
    float v0 = __uint_as_float(c0.y);
    uint32 x0 = E[(size_t)c0.x*64 + lane];
    ax += v0*bflo(x0); ay += v0*bfhi(x0);
  }
  ((uint32*)tmp_bf)[(size_t)wid*64 + lane] = pack2(ax, ay);
}

// ------- pos tables (fp32): posK/posV packed as float4 {kx,ky,vx,vy} per (j,lane);
// posQ kept flat. pt layout: [0: pKV_u 4352][4352: pKV_i 4352][8704: posQ_u 128][8832: posQ_i 128]
__global__ void pos_proj(const float* __restrict__ pos_emb,
                         const float* __restrict__ u_in_w, const float* __restrict__ u_in_b,
                         const float* __restrict__ i_in_w, const float* __restrict__ i_in_b,
                         float* __restrict__ pt){
  int j = blockIdx.x;      // 0..16
  int m = blockIdx.y;      // 0..5
  int d = threadIdx.x;     // 0..127
  if (m >= 4 && j > 0) return;
  const float* w; const float* b; int roff;
  switch (m){
    case 0: w=u_in_w; b=u_in_b; roff=128; break; // posK_u
    case 1: w=u_in_w; b=u_in_b; roff=256; break; // posV_u
    case 2: w=i_in_w; b=i_in_b; roff=128; break; // posK_i
    case 3: w=i_in_w; b=i_in_b; roff=256; break; // posV_i
    case 4: w=u_in_w; b=u_in_b; roff=0;   break; // posQ_u
    default:w=i_in_w; b=i_in_b; roff=0;   break; // posQ_i
  }
  int row = roff + d;
  float acc = b[row];
  for (int c = 0; c < DD; c++) acc += pos_emb[j*DD + c] * w[row*DD + c];
  if (m < 4){
    int base = (m >= 2) ? 4352 : 0;
    int voff = (m & 1) ? 2 : 0;
    pt[base + (j*64 + (d>>1))*4 + voff + (d&1)] = acc;
  } else {
    pt[8704 + (m-4)*128 + d] = acc;
  }
}

// ---- wave-private LDS transpose of a 16x128 MFMA C-tile, then coalesced bf16 stores ----
// stride parameterized so K and V can interleave per row (KV table, stride 256).
static __device__ __forceinline__ void tile_store_bf16(float* __restrict__ T,
    const f32x4* acc, ushort_t* __restrict__ dst, int row0, int jg, int lr, int l,
    int stride){
  #pragma unroll
  for (int r=0;r<4;r++){
    int row = jg*4 + r;
    #pragma unroll
    for (int ct=0;ct<8;ct++) T[row*132 + ct*16 + lr] = acc[ct][r];
  }
  // wave-private: no barrier needed, compiler orders ds via lgkmcnt
  #pragma unroll
  for (int i=0;i<4;i++){
    int row = l & 15;
    int p = (l >> 4) + 4*i;          // 16B-pair index 0..15 (8 cols each)
    const float* src = &T[row*132 + p*8];
    float4 a = *(const float4*)src;
    float4 b = *(const float4*)(src + 4);
    uint4 w = make_uint4(pack2(a.x,a.y), pack2(a.z,a.w), pack2(b.x,b.y), pack2(b.z,b.w));
    *(uint4*)&dst[(size_t)(row0 + row)*stride + p*8] = w;
  }
}

// ------- 5-in-1 GEMM: A-frags register-resident, reused across 5 weight matrices;
// weights staged global->LDS (XOR-swizzled). K/V outputs interleave into KV tables. ------
__global__ __launch_bounds__(256,3) void gemm5(const ushort_t* __restrict__ A,
    const ushort_t* __restrict__ wbf, ushort_t* __restrict__ Qb,
    ushort_t* __restrict__ KVu, ushort_t* __restrict__ KVi){
  __shared__ ushort_t wlds[8192];          // 16KB: one half-matrix (64 rows x 128 k)
  __shared__ float   tlds[4][16*132];      // 33.8KB transpose buffers (wave-private)
  int tid = threadIdx.x;
  int wvi = tid >> 6, l = tid & 63, lr = l & 15, jg = l >> 4;
  int row0 = blockIdx.x*64 + wvi*16;
  bool isU = (blockIdx.x*64) < USER_N;     // block-uniform (64 | 40000)

  // A fragments: 16 rows x 128 k in registers, reused for all 5 matrices
  const bf16x8* Av = (const bf16x8*)A;
  bf16x8 aFrag[4];
  #pragma unroll
  for (int kc = 0; kc < 4; kc++)
    aFrag[kc] = Av[(size_t)(row0 + lr)*16 + kc*4 + jg];

  const ushort_t* Wm[5];
  ushort_t* Dm[5];
  int St[5];
  Wm[0] = isU ? wbf : (wbf + 3*16384);  Dm[0] = Qb;        St[0] = 128; // wq
  Wm[1] = wbf + 16384;                  Dm[1] = KVu;       St[1] = 256; // wk_u -> K half
  Wm[2] = wbf + 2*16384;                Dm[2] = KVu + 128; St[2] = 256; // wv_u -> V half
  Wm[3] = wbf + 4*16384;                Dm[3] = KVi;       St[3] = 256; // wk_i
  Wm[4] = wbf + 5*16384;                Dm[4] = KVi + 128; St[4] = 256; // wv_i

  #pragma unroll
  for (int m = 0; m < 5; m++){
    f32x4 acc[8];
    #pragma unroll
    for (int c=0;c<8;c++) acc[c]=(f32x4){0,0,0,0};
    #pragma unroll
    for (int h = 0; h < 2; h++){
      __syncthreads();                               // prev readers done
      // stage half h: rows 64h..64h+63 of W (16KB), swizzled byte ^= (row&7)<<4
      const uint4* src = (const uint4*)(Wm[m] + h*8192);
      #pragma unroll
      for (int r = 0; r < 4; r++){
        int u = r*256 + tid;                         // 16B unit 0..1023
        uint32 sw = ((uint32)u*16) ^ (((uint32)(u>>4)&7u)<<4);
        *(uint4*)((char*)wlds + sw) = src[u];
      }
      __syncthreads();                               // staging visible
      #pragma unroll
      for (int kc = 0; kc < 4; kc++){
        #pragma unroll
        for (int ct = 0; ct < 4; ct++){
          uint32 rowh = (uint32)(ct*16 + lr);
          uint32 byte = (rowh*256u + (uint32)(kc*4 + jg)*16u) ^ ((rowh&7u)<<4);
          bf16x8 b = *(const bf16x8*)((const char*)wlds + byte);
          acc[h*4+ct] = __builtin_amdgcn_mfma_f32_16x16x32_bf16(aFrag[kc], b, acc[h*4+ct], 0, 0, 0);
        }
      }
    }
    tile_store_bf16(tlds[wvi], acc, Dm[m], row0, jg, lr, l, St[m]);
  }
}

// ---------------- out-projection (wave-uniform weight select) + coalesced epilogue -------
__global__ __launch_bounds__(256,4) void out_all(const ushort_t* __restrict__ A,
    const ushort_t* __restrict__ wo_u, const ushort_t* __restrict__ wo_i,
    const float* __restrict__ bu, const float* __restrict__ bi_,
    const ushort_t* __restrict__ resid_bf, ushort_t* __restrict__ e_bf,
    float* __restrict__ total, float* __restrict__ total2){
  __shared__ float lds[4][16*132];
  int tid = threadIdx.x;
  int wvi = tid >> 6, l = tid & 63, lr = l & 15, jg = l >> 4;
  int row0 = blockIdx.x*64 + wvi*16;
  bool isU = row0 < USER_N;
  const bf16x8* Av = (const bf16x8*)A;
  const bf16x8* Bw = (const bf16x8*)(isU ? wo_u : wo_i);
  const float*  bias = isU ? bu : bi_;
  f32x4 acc[8];
  #pragma unroll
  for (int c=0;c<8;c++) acc[c]=(f32x4){0,0,0,0};
  #pragma unroll
  for (int kc = 0; kc < 4; kc++){
    int ko = kc*4 + jg;
    bf16x8 a = Av[(size_t)(row0 + lr)*16 + ko];
    #pragma unroll
    for (int ct=0;ct<8;ct++)
      acc[ct] = __builtin_amdgcn_mfma_f32_16x16x32_bf16(a, Bw[(size_t)(ct*16+lr)*16 + ko], acc[ct], 0, 0, 0);
  }
  float* T = lds[wvi];
  #pragma unroll
  for (int r=0;r<4;r++){
    int row = jg*4 + r;
    #pragma unroll
    for (int ct=0;ct<8;ct++) T[row*132 + ct*16 + lr] = acc[ct][r];
  }
  #pragma unroll
  for (int i=0;i<4;i++){
    int row = l & 15;
    int p = (l >> 4) + 4*i;
    int grow = row0 + row;
    size_t o = (size_t)grow*128 + p*8;
    const float* src = &T[row*132 + p*8];
    float4 a = *(const float4*)src;
    float4 b = *(const float4*)(src + 4);
    float4 ba = *(const float4*)&bias[p*8];
    float4 bb = *(const float4*)&bias[p*8 + 4];
    uint4 rr = *(const uint4*)&resid_bf[o];
    a.x += ba.x + bflo(rr.x); a.y += ba.y + bfhi(rr.x);
    a.z += ba.z + bflo(rr.y); a.w += ba.w + bfhi(rr.y);
    b.x += bb.x + bflo(rr.z); b.y += bb.y + bfhi(rr.z);
    b.z += bb.z + bflo(rr.w); b.w += bb.w + bfhi(rr.w);
    *(uint4*)&e_bf[o] = make_uint4(pack2(a.x,a.y), pack2(a.z,a.w), pack2(b.x,b.y), pack2(b.z,b.w));
    float4 t0 = *(const float4*)&total[o];
    float4 t1 = *(const float4*)&total[o + 4];
    t0.x += a.x; t0.y += a.y; t0.z += a.z; t0.w += a.w;
    t1.x += b.x; t1.y += b.y; t1.z += b.z; t1.w += b.w;
    *(float4*)&total[o]     = t0;
    *(float4*)&total[o + 4] = t1;
    if (total2){
      *(float4*)&total2[o]     = t0;
      *(float4*)&total2[o + 4] = t1;
    }
  }
}

// ------ attention: 2 waves per node, LDS softmax merge; XCD-partitioned node mapping.
// bid%8<4 -> user pairs, else item pairs (round-robin bid->XCD): each XCD gathers from
// ONE 41MB KV table; concave coverage => per-XCD compulsory fetch drops ~33%. ------------
__global__ __launch_bounds__(256) void attn_kernel(const ushort_t* __restrict__ QP,
    const ushort_t* __restrict__ KVu, const ushort_t* __restrict__ KVi,
    const int* __restrict__ samples, const float* __restrict__ pt,
    ushort_t* __restrict__ O){
  __shared__ float4 red[2][2][64];
  int tid = threadIdx.x;
  int wv = tid >> 6, lane = tid & 63;
  int s = wv >> 1, half = wv & 1;
  int bid = blockIdx.x;                        // 40000 blocks, 5000 per XCD slot
  int x = bid & 7, q = bid >> 3;               // q < 5000
  int pairI = (x < 4) ? (q*4 + x) : (20000 + q*4 + (x - 4));
  int n = pairI*2 + s;
  bool isU = pairI < 20000;                    // block-uniform
  const uint32* KV2 = (const uint32*)(isU ? KVu : KVi);
  const float4* pKV = (const float4*)(pt + (isU ? 0 : 4352));
  const float2* pQ2 = (const float2*)(pt + 8704 + (isU ? 0 : 128));
  int smp = (lane < KK) ? samples[(size_t)n*KK + lane] : 0;
  const int j0  = half ? 9 : 0;
  const int cnt = half ? 8 : 9;
  // issue this wave's gathers up front (shared base per j: K at +0, V at +64 words)
  uint32 ku[9], vu[9];
  #pragma unroll
  for (int t = 0; t < 9; t++){
    if (t < cnt){
      int j = j0 + t;
      int row = (j == 0) ? n : __shfl(smp, j-1, 64);
      size_t o = (size_t)row*128 + lane;
      ku[t] = KV2[o];
      vu[t] = KV2[o + 64];
    }
  }
  float2 pq = pQ2[lane];
  uint32 qu = ((const uint32*)QP)[(size_t)n*64 + lane];
  float qx = bflo(qu) + pq.x, qy = bfhi(qu) + pq.y;
  float sc[9], vx[9], vy[9];
  #pragma unroll
  for (int t = 0; t < 9; t++){
    if (t < cnt){
      int j = j0 + t;
      float4 pkv = pKV[j*64 + lane];           // {kx,ky,vx,vy} one 16B load
      float kx = bflo(ku[t]) + pkv.x, ky = bfhi(ku[t]) + pkv.y;
      vx[t] = bflo(vu[t]) + pkv.z; vy[t] = bfhi(vu[t]) + pkv.w;
      float p = qx*kx + qy*ky;                 // head = lane>>4 (dims 2*lane, 2*lane+1)
      p += __shfl_xor(p, 1, 64);
      p += __shfl_xor(p, 2, 64);
      p += __shfl_xor(p, 4, 64);
      p += __shfl_xor(p, 8, 64);
      sc[t] = p * 0.17677669529663687f;        // 1/sqrt(32)
    } else sc[t] = -1e30f;
  }
  float m = sc[0];
  #pragma unroll
  for (int t = 1; t < 9; t++) m = fmaxf(m, sc[t]);
  float ss = 0.f, ox = 0.f, oy = 0.f;
  #pragma unroll
  for (int t = 0; t < 9; t++){
    if (t < cnt){
      float w = __expf(sc[t] - m);
      ss += w;
      ox += w*vx[t];
      oy += w*vy[t];
    }
  }
  red[s][half][lane] = make_float4(m, ss, ox, oy);
  __syncthreads();
  if (half == 0){
    float4 a = red[s][0][lane];
    float4 b = red[s][1][lane];
    float mm = fmaxf(a.x, b.x);
    float ea = __expf(a.x - mm), eb = __expf(b.x - mm);
    float inv = 1.f / (a.y*ea + b.y*eb);
    float fx = (a.z*ea + b.z*eb)*inv;
    float fy = (a.w*ea + b.w*eb)*inv;
    ((uint32*)O)[(size_t)n*64 + lane] = pack2(fx, fy);
  }
}

extern "C" void kernel_launch(void* const* d_in, const int* in_sizes, int n_in,
                              void* d_out, int out_size, void* d_ws, size_t ws_size,
                              hipStream_t stream){
  const int*   adj_rows = (const int*)d_in[0];
  const int*   adj_cols = (const int*)d_in[1];
  const float* adj_vals = (const float*)d_in[2];
  const int*   samples  = (const int*)d_in[3];
  const float* user_emb = (const float*)d_in[4];
  const float* item_emb = (const float*)d_in[5];
  const float* pos_emb  = (const float*)d_in[6];
  const float* u_in_w   = (const float*)d_in[7];
  const float* u_in_b   = (const float*)d_in[8];
  const float* u_out_w  = (const float*)d_in[9];
  const float* u_out_b  = (const float*)d_in[10];
  const float* i_in_w   = (const float*)d_in[11];
  const float* i_in_b   = (const float*)d_in[12];
  const float* i_out_w  = (const float*)d_in[13];
  const float* i_out_b  = (const float*)d_in[14];
  float* out = (float*)d_out;

  char* ws = (char*)d_ws;
  size_t off = 0;
  auto alloc = [&](size_t bytes)->char*{
    char* p = ws + off; off += (bytes + 255) & ~(size_t)255; return p;
  };
  ushort_t* tmp_bf  = (ushort_t*)alloc((size_t)NN*DD*2);
  ushort_t* e_bf    = (ushort_t*)alloc((size_t)NN*DD*2);
  ushort_t* Qb      = (ushort_t*)alloc((size_t)NN*DD*2);
  ushort_t* KVu     = (ushort_t*)alloc((size_t)NN*DD*4);   // K|V interleaved, 41MB
  ushort_t* KVi     = (ushort_t*)alloc((size_t)NN*DD*4);
  ushort_t* Ob      = (ushort_t*)alloc((size_t)NN*DD*2);
  uint2*    csr     = (uint2*)   alloc((size_t)EE*8);
  int*      cntG    = (int*)     alloc((size_t)(NB*NG)*4);
  int*      baseG   = (int*)     alloc((size_t)(NB*NG)*4);
  int*      row_ptr = (int*)     alloc((size_t)(NN+1)*4);
  int*      bsum    = (int*)     alloc(320*4);
  int*      bpre    = (int*)     alloc(320*4);
  float*    pt      = (float*)   alloc((size_t)8960*4);
  ushort_t* wbf     = (ushort_t*)alloc((size_t)131072*2);

  // kv (12.8MB) aliases Ob: Ob first written by attn, long after s4 consumed kv.
  uint2* kv = (uint2*)Ob;

  ushort_t* wo_u = wbf + 6*16384;
  ushort_t* wo_i = wbf + 7*16384;

  init_e_total<<<NN*DD/4/256, 256, 0, stream>>>(user_emb, item_emb, e_bf, out);
  // ---- CSR build: single-level row counting sort ----
  s1_hist<<<NG, 256, 0, stream>>>(adj_rows, cntG);
  sum313<<<NB, 256, 0, stream>>>(cntG, bsum);
  scanb<<<1, 512, 0, stream>>>(bsum, bpre);
  scanE<<<NB, 256, 0, stream>>>(cntG, bpre, baseG);
  s3_scatter<<<NG, 256, 0, stream>>>(adj_rows, adj_cols, adj_vals, baseG, kv);
  s4_sort<<<NB, 256, 0, stream>>>(baseG, kv, row_ptr, csr);
  pos_proj<<<dim3(17,6), 128, 0, stream>>>(pos_emb, u_in_w, u_in_b, i_in_w, i_in_b, pt);
  cvt_weights<<<512, 256, 0, stream>>>(u_in_w, i_in_w, u_out_w, i_out_w, wbf);

  for (int it = 0; it < 2; it++){
    float* tot2 = (it == 1) ? (out + (size_t)NN*DD) : nullptr;
    spmm_kernel<<<NN/4, 256, 0, stream>>>(row_ptr, csr, e_bf, tmp_bf);
    gemm5<<<NN/64, 256, 0, stream>>>(tmp_bf, wbf, Qb, KVu, KVi);
    attn_kernel<<<NN/2, 256, 0, stream>>>(Qb, KVu, KVi, samples, pt, Ob);
    out_all<<<NN/64, 256, 0, stream>>>(Ob, wo_u, wo_i, u_out_b, i_out_b,
                                       tmp_bf, e_bf, out, tot2);
  }
}